// Round 1
// 1514.605 us; speedup vs baseline: 1.1521x; 1.1521x over previous
//
#include <hip/hip_runtime.h>
#include <math.h>

#define S_LEN 1024
#define BATCH 8
#define EMB 512
#define NHEAD 8
#define DHEAD 64
#define DHID 256
#define SDEPTH 48
#define SWIDTH 96
#define DFF 2048
#define DSS 128

typedef unsigned short u16;
typedef __attribute__((ext_vector_type(4))) float f32x4;
typedef __attribute__((ext_vector_type(8))) unsigned short u16x8;
typedef __attribute__((ext_vector_type(8))) __bf16 bf16x8;

// nonsat(x): solve y^3/3 + y = x by Newton (fully converged == reference).
__device__ __forceinline__ float nonsat_f(float x) {
  float y = x;
#pragma unroll
  for (int i = 0; i < 20; ++i) {
    float y2 = y * y;
    y = __fdividef(0.6666666667f * y * y2 + x, y2 + 1.0f);
  }
  return y;
}

// ---- fp32 -> bf16 (RTNE) split helpers -------------------------------------
__device__ __forceinline__ u16 f2bf(float f) {
  unsigned u = __float_as_uint(f);
  unsigned r = (u + 0x7fffu + ((u >> 16) & 1u)) >> 16;
  return (u16)r;
}
__device__ __forceinline__ float bf2f(u16 h) {
  return __uint_as_float(((unsigned)h) << 16);
}
__device__ __forceinline__ void split1(float f, u16& hh, u16& ll) {
  hh = f2bf(f);
  ll = f2bf(f - bf2f(hh));
}
// 16 floats (4x float4) -> 2x u16x8 hi + 2x u16x8 lo
__device__ __forceinline__ void cvt16(const float4 v[4], u16x8 hi[2], u16x8 lo[2]) {
#pragma unroll
  for (int j = 0; j < 4; ++j) {
    const float f[4] = {v[j].x, v[j].y, v[j].z, v[j].w};
#pragma unroll
    for (int e = 0; e < 4; ++e) {
      u16 hh, ll;
      split1(f[e], hh, ll);
      hi[j >> 1][(j & 1) * 4 + e] = hh;
      lo[j >> 1][(j & 1) * 4 + e] = ll;
    }
  }
}

__device__ __forceinline__ f32x4 mfma_bf16(u16x8 a, u16x8 b, f32x4 c) {
  return __builtin_amdgcn_mfma_f32_16x16x32_bf16(
      __builtin_bit_cast(bf16x8, a), __builtin_bit_cast(bf16x8, b), c, 0, 0, 0);
}

// ---------------- split-bf16 MFMA GEMM: C[M,N] (+)= A[M,K] @ W[N,K]^T + bias
// Emulated fp32 precision: A = Ah + Al (bf16 pair), C ~= Ah*Wh + Ah*Wl + Al*Wh.
// perm: 0 identity; 1: A row = ((m&1023)<<3)|(m>>10); 2: A row = ((m&7)<<10)|(m>>3)
// flags: bit0 = accumulate into C, bit1 = nonsat epilogue
// Requires: M % 128 == 0, K % 32 == 0. N arbitrary (guarded).
// Block: 256 threads = 4 waves (2x2), each wave computes a 64x64 sub-tile as
// 4x4 fragments of 16x16x32 MFMA. LDS rows padded to 40 u16 (80 B) so fragment
// b128 reads spread across bank quads.
__global__ __launch_bounds__(256)
void gemm_mfma(const float* __restrict__ A, int lda, int perm,
               const float* __restrict__ W, int ldw,
               const float* __restrict__ bias,
               float* __restrict__ C,
               int M, int N, int K, int flags) {
  __shared__ __align__(16) u16 Ah[128][40];
  __shared__ __align__(16) u16 Al[128][40];
  __shared__ __align__(16) u16 Wh[128][40];
  __shared__ __align__(16) u16 Wl[128][40];

  int t = threadIdx.x;
  int l = t & 63, w = t >> 6;
  int wr = w >> 1, wc = w & 1;          // 2x2 wave grid
  int m0 = blockIdx.y * 128, n0 = blockIdx.x * 128;

  // staging coords: thread stages 16 floats of one row-half for A and W
  int r = t >> 1, h = t & 1;
  int mrow = m0 + r;
  int arow = mrow;
  if (perm == 1)      arow = ((mrow & 1023) << 3) | (mrow >> 10);
  else if (perm == 2) arow = ((mrow & 7) << 10) | (mrow >> 3);
  const float* Ap = A + (size_t)arow * lda + h * 16;
  int nrow = n0 + r;
  const float* Wp = W + (size_t)nrow * ldw + h * 16;
  bool wok = nrow < N;

  f32x4 acc[4][4];
#pragma unroll
  for (int mt = 0; mt < 4; ++mt)
#pragma unroll
    for (int nt = 0; nt < 4; ++nt)
      acc[mt][nt] = (f32x4){0.f, 0.f, 0.f, 0.f};

  // prologue: prefetch tile k0=0 into registers
  float4 la[4], lw[4];
#pragma unroll
  for (int j = 0; j < 4; ++j) {
    la[j] = *(const float4*)(Ap + j * 4);
    lw[j] = wok ? *(const float4*)(Wp + j * 4)
                : make_float4(0.f, 0.f, 0.f, 0.f);
  }

  int ri = l & 15;
  int kq = (l >> 4) * 8;  // u16 offset of this lane's 8-element K chunk

  for (int k0 = 0; k0 < K; k0 += 32) {
    // convert the prefetched tile
    u16x8 cah[2], cal[2], cwh[2], cwl[2];
    cvt16(la, cah, cal);
    cvt16(lw, cwh, cwl);

    __syncthreads();  // previous iteration's fragment reads done
    *(u16x8*)&Ah[r][h * 16]     = cah[0];
    *(u16x8*)&Ah[r][h * 16 + 8] = cah[1];
    *(u16x8*)&Al[r][h * 16]     = cal[0];
    *(u16x8*)&Al[r][h * 16 + 8] = cal[1];
    *(u16x8*)&Wh[r][h * 16]     = cwh[0];
    *(u16x8*)&Wh[r][h * 16 + 8] = cwh[1];
    *(u16x8*)&Wl[r][h * 16]     = cwl[0];
    *(u16x8*)&Wl[r][h * 16 + 8] = cwl[1];

    // issue next tile's global loads; latency hides under the MFMA phase
    if (k0 + 32 < K) {
#pragma unroll
      for (int j = 0; j < 4; ++j) {
        la[j] = *(const float4*)(Ap + (k0 + 32) + j * 4);
        lw[j] = wok ? *(const float4*)(Wp + (k0 + 32) + j * 4)
                    : make_float4(0.f, 0.f, 0.f, 0.f);
      }
    }
    __syncthreads();  // LDS tile ready

    u16x8 fah[4], fal[4], fbh[4], fbl[4];
#pragma unroll
    for (int mt = 0; mt < 4; ++mt) {
      int row = wr * 64 + mt * 16 + ri;
      fah[mt] = *(const u16x8*)&Ah[row][kq];
      fal[mt] = *(const u16x8*)&Al[row][kq];
    }
#pragma unroll
    for (int nt = 0; nt < 4; ++nt) {
      int row = wc * 64 + nt * 16 + ri;
      fbh[nt] = *(const u16x8*)&Wh[row][kq];
      fbl[nt] = *(const u16x8*)&Wl[row][kq];
    }
#pragma unroll
    for (int mt = 0; mt < 4; ++mt)
#pragma unroll
      for (int nt = 0; nt < 4; ++nt) {
        f32x4 c = acc[mt][nt];
        c = mfma_bf16(fah[mt], fbl[nt], c);
        c = mfma_bf16(fal[mt], fbh[nt], c);
        c = mfma_bf16(fah[mt], fbh[nt], c);
        acc[mt][nt] = c;
      }
  }

  // epilogue: D row = (lane>>4)*4 + reg, D col = lane&15 (verified C/D layout)
  int rq = l >> 4;
#pragma unroll
  for (int mt = 0; mt < 4; ++mt) {
#pragma unroll
    for (int nt = 0; nt < 4; ++nt) {
      int col = n0 + wc * 64 + nt * 16 + ri;
      if (col < N) {
        float bv = bias ? bias[col] : 0.f;
        int row0 = m0 + wr * 64 + mt * 16 + rq * 4;
#pragma unroll
        for (int i = 0; i < 4; ++i) {
          size_t idx = (size_t)(row0 + i) * N + col;
          float o = acc[mt][nt][i] + bv;
          if (flags & 1) o += C[idx];
          if (flags & 2) o = nonsat_f(o);
          C[idx] = o;
        }
      }
    }
  }
}

// --------- repack Q,K,V from qkv (s,b,1536) into per-(b,h) contiguous slabs --
__global__ __launch_bounds__(256)
void repack_qkv(const float* __restrict__ qkv, float* __restrict__ Qc,
                float* __restrict__ Kc, float* __restrict__ Vc) {
  int i = blockIdx.x * 256 + threadIdx.x;  // float4 index, 1048576 total
  int d4 = i & 15;
  int t  = (i >> 4) & 1023;
  int h  = (i >> 14) & 7;
  int b  = i >> 17;
  const float4* src = (const float4*)qkv;
  size_t base = ((size_t)t * BATCH + b) * 384 + h * 16 + d4;
  size_t out  = (size_t)i;
  ((float4*)Qc)[out] = src[base];
  ((float4*)Kc)[out] = src[base + 128];
  ((float4*)Vc)[out] = src[base + 256];
}

// --------- flash-style causal attention -------------------------------------
__global__ __launch_bounds__(256)
void fattn_kernel(const float* __restrict__ Qc, const float* __restrict__ Kc,
                  const float* __restrict__ Vc, float* __restrict__ ao) {
  int qi = blockIdx.x;
  int bh = blockIdx.y;
  int b = bh >> 3, h = bh & 7;
  int t = threadIdx.x;
  int tx = t & 15, ty = t >> 4;

  __shared__ float Qs[64][68];
  __shared__ float Ks[64][68];
  __shared__ float Vs[64][68];

  const float* Qbase = Qc + ((size_t)bh * S_LEN + qi * 64) * DHEAD;
#pragma unroll
  for (int f = t, it = 0; it < 4; ++it, f += 256) {
    int r = f >> 4, c4 = (f & 15) << 2;
    float4 q = *(const float4*)(Qbase + r * DHEAD + c4);
    Qs[c4 + 0][r] = q.x * 0.125f;
    Qs[c4 + 1][r] = q.y * 0.125f;
    Qs[c4 + 2][r] = q.z * 0.125f;
    Qs[c4 + 3][r] = q.w * 0.125f;
  }

  float o[4][4] = {{0.f}};
  float m_i[4] = {-1e30f, -1e30f, -1e30f, -1e30f};
  float l_i[4] = {0.f, 0.f, 0.f, 0.f};

  for (int kt = 0; kt <= qi; ++kt) {
    const float* Kbase = Kc + ((size_t)bh * S_LEN + kt * 64) * DHEAD;
    const float* Vbase = Vc + ((size_t)bh * S_LEN + kt * 64) * DHEAD;
    __syncthreads();
#pragma unroll
    for (int f = t, it = 0; it < 4; ++it, f += 256) {
      int r = f >> 4, c4 = (f & 15) << 2;
      float4 k4 = *(const float4*)(Kbase + r * DHEAD + c4);
      Ks[c4 + 0][r] = k4.x;
      Ks[c4 + 1][r] = k4.y;
      Ks[c4 + 2][r] = k4.z;
      Ks[c4 + 3][r] = k4.w;
      float4 v4 = *(const float4*)(Vbase + r * DHEAD + c4);
      *(float4*)&Vs[r][c4] = v4;
    }
    __syncthreads();

    float s[4][4] = {{0.f}};
#pragma unroll 16
    for (int d = 0; d < 64; ++d) {
      float a0 = Qs[d][ty * 4 + 0], a1 = Qs[d][ty * 4 + 1];
      float a2 = Qs[d][ty * 4 + 2], a3 = Qs[d][ty * 4 + 3];
      float w0 = Ks[d][tx * 4 + 0], w1 = Ks[d][tx * 4 + 1];
      float w2 = Ks[d][tx * 4 + 2], w3 = Ks[d][tx * 4 + 3];
      s[0][0] += a0 * w0; s[0][1] += a0 * w1; s[0][2] += a0 * w2; s[0][3] += a0 * w3;
      s[1][0] += a1 * w0; s[1][1] += a1 * w1; s[1][2] += a1 * w2; s[1][3] += a1 * w3;
      s[2][0] += a2 * w0; s[2][1] += a2 * w1; s[2][2] += a2 * w2; s[2][3] += a2 * w3;
      s[3][0] += a3 * w0; s[3][1] += a3 * w1; s[3][2] += a3 * w2; s[3][3] += a3 * w3;
    }

    if (kt == qi) {
#pragma unroll
      for (int i = 0; i < 4; ++i)
#pragma unroll
        for (int j = 0; j < 4; ++j)
          if (tx * 4 + j > ty * 4 + i) s[i][j] = -1e30f;
    }

    float p[4][4];
    float alpha[4], rsum[4];
#pragma unroll
    for (int i = 0; i < 4; ++i) {
      float rmax = fmaxf(fmaxf(s[i][0], s[i][1]), fmaxf(s[i][2], s[i][3]));
      rmax = fmaxf(rmax, __shfl_xor(rmax, 1));
      rmax = fmaxf(rmax, __shfl_xor(rmax, 2));
      rmax = fmaxf(rmax, __shfl_xor(rmax, 4));
      rmax = fmaxf(rmax, __shfl_xor(rmax, 8));
      float mn = fmaxf(m_i[i], rmax);
      alpha[i] = __expf(m_i[i] - mn);
      m_i[i] = mn;
      float rs = 0.f;
#pragma unroll
      for (int j = 0; j < 4; ++j) {
        p[i][j] = __expf(s[i][j] - mn);
        rs += p[i][j];
      }
      rs += __shfl_xor(rs, 1);
      rs += __shfl_xor(rs, 2);
      rs += __shfl_xor(rs, 4);
      rs += __shfl_xor(rs, 8);
      rsum[i] = rs;
    }
#pragma unroll
    for (int i = 0; i < 4; ++i) {
      l_i[i] = l_i[i] * alpha[i] + rsum[i];
#pragma unroll
      for (int j = 0; j < 4; ++j) o[i][j] *= alpha[i];
    }

    __syncthreads();
#pragma unroll
    for (int j = 0; j < 4; ++j) {
      float4 pj = make_float4(p[0][j], p[1][j], p[2][j], p[3][j]);
      *(float4*)&Ks[tx * 4 + j][ty * 4] = pj;
    }
    __syncthreads();

#pragma unroll 16
    for (int k = 0; k < 64; ++k) {
      float a0 = Ks[k][ty * 4 + 0], a1 = Ks[k][ty * 4 + 1];
      float a2 = Ks[k][ty * 4 + 2], a3 = Ks[k][ty * 4 + 3];
      float v0 = Vs[k][tx * 4 + 0], v1 = Vs[k][tx * 4 + 1];
      float v2 = Vs[k][tx * 4 + 2], v3 = Vs[k][tx * 4 + 3];
      o[0][0] += a0 * v0; o[0][1] += a0 * v1; o[0][2] += a0 * v2; o[0][3] += a0 * v3;
      o[1][0] += a1 * v0; o[1][1] += a1 * v1; o[1][2] += a1 * v2; o[1][3] += a1 * v3;
      o[2][0] += a2 * v0; o[2][1] += a2 * v1; o[2][2] += a2 * v2; o[2][3] += a2 * v3;
      o[3][0] += a3 * v0; o[3][1] += a3 * v1; o[3][2] += a3 * v2; o[3][3] += a3 * v3;
    }
  }

#pragma unroll
  for (int i = 0; i < 4; ++i) {
    float inv = __fdividef(1.f, l_i[i]);
    int s_glob = qi * 64 + ty * 4 + i;
    float4 r = make_float4(o[i][0] * inv, o[i][1] * inv, o[i][2] * inv, o[i][3] * inv);
    *(float4*)(ao + ((size_t)s_glob * BATCH + b) * EMB + h * DHEAD + tx * 4) = r;
  }
}

// --------- layernorm over E=512 of (xa+xb), optional nonsat ------------------
__global__ __launch_bounds__(256)
void ln_kernel(const float* __restrict__ xa, const float* __restrict__ xb,
               const float* __restrict__ g, const float* __restrict__ bet,
               float* __restrict__ out, int act) {
  int row = blockIdx.x;
  int t = threadIdx.x;
  size_t base = (size_t)row * EMB;
  float v0 = xa[base + t] + xb[base + t];
  float v1 = xa[base + t + 256] + xb[base + t + 256];
  float s = v0 + v1;
  float s2 = v0 * v0 + v1 * v1;
#pragma unroll
  for (int off = 32; off >= 1; off >>= 1) {
    s += __shfl_xor(s, off);
    s2 += __shfl_xor(s2, off);
  }
  __shared__ float ss[4], ss2[4];
  int w = t >> 6;
  if ((t & 63) == 0) { ss[w] = s; ss2[w] = s2; }
  __syncthreads();
  s = ss[0] + ss[1] + ss[2] + ss[3];
  s2 = ss2[0] + ss2[1] + ss2[2] + ss2[3];
  float mu = s * (1.f / EMB);
  float var = s2 * (1.f / EMB) - mu * mu;
  float rs = rsqrtf(var + 1e-5f);
  float o0 = (v0 - mu) * rs * g[t] + bet[t];
  float o1 = (v1 - mu) * rs * g[t + 256] + bet[t + 256];
  if (act) { o0 = nonsat_f(o0); o1 = nonsat_f(o1); }
  out[base + t] = o0;
  out[base + t + 256] = o1;
}

// --------- softmax over 128 (one wave per row) -------------------------------
__global__ __launch_bounds__(256)
void softmax128_kernel(float* __restrict__ L) {
  int row = blockIdx.x * 4 + (threadIdx.x >> 6);
  int lane = threadIdx.x & 63;
  float* p = L + (size_t)row * DSS;
  float a = p[lane], c = p[lane + 64];
  float m = fmaxf(a, c);
#pragma unroll
  for (int off = 32; off >= 1; off >>= 1) m = fmaxf(m, __shfl_xor(m, off));
  float e0 = __expf(a - m), e1 = __expf(c - m);
  float ssum = e0 + e1;
#pragma unroll
  for (int off = 32; off >= 1; off >>= 1) ssum += __shfl_xor(ssum, off);
  float inv = __fdividef(1.f, ssum);
  p[lane] = e0 * inv;
  p[lane + 64] = e1 * inv;
}

// --------- x2 = 0.5*(x1 + y) -------------------------------------------------
__global__ __launch_bounds__(256)
void avg_kernel(const float* __restrict__ a, const float* __restrict__ b,
                float* __restrict__ o) {
  int i = blockIdx.x * 256 + threadIdx.x;
  float4 x = ((const float4*)a)[i], y = ((const float4*)b)[i];
  float4 r = make_float4(0.5f * (x.x + y.x), 0.5f * (x.y + y.y),
                         0.5f * (x.z + y.z), 0.5f * (x.w + y.w));
  ((float4*)o)[i] = r;
}

// --------- controls = softmax3(hidden @ A_w^T + A_b), one wave per row -------
__global__ __launch_bounds__(256)
void controls_kernel(const float* __restrict__ hidden, const float* __restrict__ Aw,
                     const float* __restrict__ Ab, float* __restrict__ ctrl) {
  int row = blockIdx.x * 4 + (threadIdx.x >> 6);
  int lane = threadIdx.x & 63;
  const float* h = hidden + (size_t)row * DHID;
  float h0 = h[lane], h1 = h[lane + 64], h2 = h[lane + 128], h3 = h[lane + 192];
  float p0 = h0 * Aw[lane] + h1 * Aw[lane + 64] + h2 * Aw[lane + 128] + h3 * Aw[lane + 192];
  float p1 = h0 * Aw[256 + lane] + h1 * Aw[320 + lane] + h2 * Aw[384 + lane] + h3 * Aw[448 + lane];
  float p2 = h0 * Aw[512 + lane] + h1 * Aw[576 + lane] + h2 * Aw[640 + lane] + h3 * Aw[704 + lane];
#pragma unroll
  for (int off = 32; off >= 1; off >>= 1) {
    p0 += __shfl_xor(p0, off);
    p1 += __shfl_xor(p1, off);
    p2 += __shfl_xor(p2, off);
  }
  if (lane == 0) {
    p0 += Ab[0]; p1 += Ab[1]; p2 += Ab[2];
    float m = fmaxf(p0, fmaxf(p1, p2));
    float e0 = __expf(p0 - m), e1 = __expf(p1 - m), e2 = __expf(p2 - m);
    float inv = __fdividef(1.f, e0 + e1 + e2);
    ctrl[(size_t)row * 3 + 0] = e0 * inv;
    ctrl[(size_t)row * 3 + 1] = e1 * inv;
    ctrl[(size_t)row * 3 + 2] = e2 * inv;
  }
}

// --------- stack update: one block per (b,s) row -----------------------------
__global__ __launch_bounds__(256)
void stack_kernel(const float* __restrict__ sp, const float* __restrict__ si,
                  const float* __restrict__ ctrl, float* __restrict__ out) {
  int row = blockIdx.x;
  float c0 = ctrl[(size_t)row * 3 + 0];
  float c1 = ctrl[(size_t)row * 3 + 1];
  float c2 = ctrl[(size_t)row * 3 + 2];
  const float4* spr = (const float4*)(sp + (size_t)row * SDEPTH * SWIDTH);
  const float4* sir = (const float4*)(si + (size_t)row * SWIDTH);
  float4* o = (float4*)(out + (size_t)row * SDEPTH * SWIDTH);
  const int WV = SWIDTH / 4;  // 24
  for (int i = threadIdx.x; i < SDEPTH * WV; i += 256) {
    int d = i / WV;
    int w = i - d * WV;
    float4 cur = spr[i];
    float4 up = (d == 0) ? sir[w] : spr[i - WV];
    float4 dn = (d < SDEPTH - 1) ? spr[i + WV] : make_float4(0.f, 0.f, 0.f, 0.f);
    float4 r;
    r.x = c2 * cur.x + c0 * up.x + c1 * dn.x;
    r.y = c2 * cur.y + c0 * up.y + c1 * dn.y;
    r.z = c2 * cur.z + c0 * up.z + c1 * dn.z;
    r.w = c2 * cur.w + c0 * up.w + c1 * dn.w;
    o[i] = r;
  }
}

static inline void gemm(hipStream_t st, const float* A, int lda, int perm,
                        const float* W, int ldw, const float* bias, float* C,
                        int M, int N, int K, int flags) {
  dim3 g((N + 127) / 128, M / 128);
  hipLaunchKernelGGL(gemm_mfma, g, dim3(256), 0, st, A, lda, perm, W, ldw,
                     bias, C, M, N, K, flags);
}

extern "C" void kernel_launch(void* const* d_in, const int* in_sizes, int n_in,
                              void* d_out, int out_size, void* d_ws, size_t ws_size,
                              hipStream_t stream) {
  const float* x_in  = (const float*)d_in[0];
  const float* hprev = (const float*)d_in[1];
  const float* sprev = (const float*)d_in[2];
  const float* ipw   = (const float*)d_in[3];
  const float* ipb   = (const float*)d_in[4];
  const float* opw   = (const float*)d_in[5];
  const float* opb   = (const float*)d_in[6];
  const float* ln1g  = (const float*)d_in[7];
  const float* ln1b  = (const float*)d_in[8];
  const float* ln2g  = (const float*)d_in[9];
  const float* ln2b  = (const float*)d_in[10];
  const float* Ww    = (const float*)d_in[11];
  const float* Wb    = (const float*)d_in[12];
  const float* Rw    = (const float*)d_in[13];
  const float* Rb    = (const float*)d_in[14];
  const float* Pw    = (const float*)d_in[15];
  const float* Pb    = (const float*)d_in[16];
  const float* Vw    = (const float*)d_in[17];
  const float* Uw    = (const float*)d_in[18];
  const float* Aw    = (const float*)d_in[19];
  const float* Ab    = (const float*)d_in[20];
  const float* Dw    = (const float*)d_in[21];
  const float* Db    = (const float*)d_in[22];
  const float* ffiw  = (const float*)d_in[23];
  const float* ffib  = (const float*)d_in[24];
  const float* ffow  = (const float*)d_in[25];
  const float* ffob  = (const float*)d_in[26];

  float* ws     = (float*)d_ws;
  float* qkv    = ws;               // 12,582,912
  float* Kc     = ws + 12582912;    //  4,194,304
  float* Vc     = ws + 16777216;    //  4,194,304
  float* ff1    = ws;               // 16,777,216 (after attention done)
  float* bufB   = ws + 20971520;    //  4,194,304
  float* bufC   = ws + 25165824;    //  4,194,304 (Qc until out-proj overwrites)
  float* x1     = ws + 29360128;    //  4,194,304
  float* logits = ws + 33554432;    //  1,048,576
  float* si     = ws + 34603008;    //    786,432
  float* ctrl   = ws + 35389440;    //     24,576
  float* Qc     = bufC;

  float* out_x = (float*)d_out;
  float* out_h = out_x + 4194304;
  float* out_s = out_h + 2097152;

  const int M = S_LEN * BATCH;  // 8192

  // 1. qkv projection
  gemm(stream, x_in, EMB, 0, ipw, EMB, ipb, qkv, M, 3 * EMB, EMB, 0);
  // 2. repack Q/K/V contiguous per (b,h)
  hipLaunchKernelGGL(repack_qkv, dim3(4096), dim3(256), 0, stream, qkv, Qc, Kc, Vc);
  // 3. flash causal attention -> bufB (pre-out_proj)
  hipLaunchKernelGGL(fattn_kernel, dim3(S_LEN / 64, BATCH * NHEAD), dim3(256), 0,
                     stream, Qc, Kc, Vc, bufB);
  // 4. out projection -> bufC
  gemm(stream, bufB, EMB, 0, opw, EMB, opb, bufC, M, EMB, EMB, 0);
  // 5. x1 = nonsat(LN(x_in + proj))
  hipLaunchKernelGGL(ln_kernel, dim3(M), dim3(256), 0, stream, x_in, bufC, ln1g,
                     ln1b, x1, 1);
  // 6. hidden = nonsat(x1'@W^T + Wb + hprev@R^T + Rb + stack0@P^T + Pb) -> d_out
  gemm(stream, x1, EMB, 1, Ww, EMB, Wb, out_h, M, DHID, EMB, 0);
  gemm(stream, hprev, DHID, 0, Rw, DHID, Rb, out_h, M, DHID, DHID, 1);
  gemm(stream, sprev, SDEPTH * SWIDTH, 0, Pw, SWIDTH, Pb, out_h, M, DHID, SWIDTH, 1 | 2);
  // 7. logits = [x1, hidden'] @ V^T
  gemm(stream, x1, EMB, 0, Vw, EMB + DHID, nullptr, logits, M, DSS, EMB, 0);
  gemm(stream, out_h, DHID, 2, Vw + EMB, EMB + DHID, nullptr, logits, M, DSS, DHID, 1);
  // 8. softmax over 128
  hipLaunchKernelGGL(softmax128_kernel, dim3(M / 4), dim3(256), 0, stream, logits);
  // 9. y = probs @ U^T -> bufB
  gemm(stream, logits, DSS, 0, Uw, DSS, nullptr, bufB, M, EMB, DSS, 0);
  // 10. x2 = 0.5*(x1 + y) -> bufC
  hipLaunchKernelGGL(avg_kernel, dim3(4096), dim3(256), 0, stream, x1, bufB, bufC);
  // 11. stack_inp = nonsat(hidden @ D^T + Db)
  gemm(stream, out_h, DHID, 0, Dw, DHID, Db, si, M, SWIDTH, DHID, 2);
  // 12. controls
  hipLaunchKernelGGL(controls_kernel, dim3(M / 4), dim3(256), 0, stream, out_h, Aw, Ab, ctrl);
  // 13. stack update -> d_out
  hipLaunchKernelGGL(stack_kernel, dim3(M), dim3(256), 0, stream, sprev, si, ctrl, out_s);
  // 14. ff1 = nonsat(x2 @ ffi^T + ffib)   (reuses qkv/Kc region)
  gemm(stream, bufC, EMB, 0, ffiw, EMB, ffib, ff1, M, DFF, EMB, 2);
  // 15. ff2 -> bufB
  gemm(stream, ff1, DFF, 0, ffow, DFF, ffob, bufB, M, EMB, DFF, 0);
  // 16. x_out = LN(x2 + ff)
  hipLaunchKernelGGL(ln_kernel, dim3(M), dim3(256), 0, stream, bufC, bufB, ln2g,
                     ln2b, out_x, 0);
}

// Round 2
// 1464.227 us; speedup vs baseline: 1.1917x; 1.0344x over previous
//
#include <hip/hip_runtime.h>
#include <math.h>

#define S_LEN 1024
#define BATCH 8
#define EMB 512
#define NHEAD 8
#define DHEAD 64
#define DHID 256
#define SDEPTH 48
#define SWIDTH 96
#define DFF 2048
#define DSS 128

typedef unsigned short u16;
typedef __attribute__((ext_vector_type(4))) float f32x4;
typedef __attribute__((ext_vector_type(4))) unsigned short u16x4;
typedef __attribute__((ext_vector_type(8))) unsigned short u16x8;
typedef __attribute__((ext_vector_type(8))) __bf16 bf16x8;

// nonsat(x): solve y^3/3 + y = x by Newton (fully converged == reference).
__device__ __forceinline__ float nonsat_f(float x) {
  float y = x;
#pragma unroll
  for (int i = 0; i < 20; ++i) {
    float y2 = y * y;
    y = __fdividef(0.6666666667f * y * y2 + x, y2 + 1.0f);
  }
  return y;
}

// ---- fp32 -> bf16 (RTNE) split helpers -------------------------------------
__device__ __forceinline__ u16 f2bf(float f) {
  unsigned u = __float_as_uint(f);
  unsigned r = (u + 0x7fffu + ((u >> 16) & 1u)) >> 16;
  return (u16)r;
}
__device__ __forceinline__ float bf2f(u16 h) {
  return __uint_as_float(((unsigned)h) << 16);
}
__device__ __forceinline__ void split1(float f, u16& hh, u16& ll) {
  hh = f2bf(f);
  ll = f2bf(f - bf2f(hh));
}
// 16 floats (4x float4) -> 2x u16x8 hi + 2x u16x8 lo
__device__ __forceinline__ void cvt16(const float4 v[4], u16x8 hi[2], u16x8 lo[2]) {
#pragma unroll
  for (int j = 0; j < 4; ++j) {
    const float f[4] = {v[j].x, v[j].y, v[j].z, v[j].w};
#pragma unroll
    for (int e = 0; e < 4; ++e) {
      u16 hh, ll;
      split1(f[e], hh, ll);
      hi[j >> 1][(j & 1) * 4 + e] = hh;
      lo[j >> 1][(j & 1) * 4 + e] = ll;
    }
  }
}

__device__ __forceinline__ f32x4 mfma_bf16(u16x8 a, u16x8 b, f32x4 c) {
  return __builtin_amdgcn_mfma_f32_16x16x32_bf16(
      __builtin_bit_cast(bf16x8, a), __builtin_bit_cast(bf16x8, b), c, 0, 0, 0);
}

// ---------------- split-bf16 MFMA GEMM: C[M,N] (+)= A[M,K] @ W[N,K]^T + bias
// perm: 0 identity; 1: A row = ((m&1023)<<3)|(m>>10); 2: A row = ((m&7)<<10)|(m>>3)
// flags: bit0 = accumulate into C, bit1 = nonsat epilogue
__global__ __launch_bounds__(256)
void gemm_mfma(const float* __restrict__ A, int lda, int perm,
               const float* __restrict__ W, int ldw,
               const float* __restrict__ bias,
               float* __restrict__ C,
               int M, int N, int K, int flags) {
  __shared__ __align__(16) u16 Ah[128][40];
  __shared__ __align__(16) u16 Al[128][40];
  __shared__ __align__(16) u16 Wh[128][40];
  __shared__ __align__(16) u16 Wl[128][40];

  int t = threadIdx.x;
  int l = t & 63, w = t >> 6;
  int wr = w >> 1, wc = w & 1;          // 2x2 wave grid
  int m0 = blockIdx.y * 128, n0 = blockIdx.x * 128;

  int r = t >> 1, h = t & 1;
  int mrow = m0 + r;
  int arow = mrow;
  if (perm == 1)      arow = ((mrow & 1023) << 3) | (mrow >> 10);
  else if (perm == 2) arow = ((mrow & 7) << 10) | (mrow >> 3);
  const float* Ap = A + (size_t)arow * lda + h * 16;
  int nrow = n0 + r;
  const float* Wp = W + (size_t)nrow * ldw + h * 16;
  bool wok = nrow < N;

  f32x4 acc[4][4];
#pragma unroll
  for (int mt = 0; mt < 4; ++mt)
#pragma unroll
    for (int nt = 0; nt < 4; ++nt)
      acc[mt][nt] = (f32x4){0.f, 0.f, 0.f, 0.f};

  float4 la[4], lw[4];
#pragma unroll
  for (int j = 0; j < 4; ++j) {
    la[j] = *(const float4*)(Ap + j * 4);
    lw[j] = wok ? *(const float4*)(Wp + j * 4)
                : make_float4(0.f, 0.f, 0.f, 0.f);
  }

  int ri = l & 15;
  int kq = (l >> 4) * 8;

  for (int k0 = 0; k0 < K; k0 += 32) {
    u16x8 cah[2], cal[2], cwh[2], cwl[2];
    cvt16(la, cah, cal);
    cvt16(lw, cwh, cwl);

    __syncthreads();
    *(u16x8*)&Ah[r][h * 16]     = cah[0];
    *(u16x8*)&Ah[r][h * 16 + 8] = cah[1];
    *(u16x8*)&Al[r][h * 16]     = cal[0];
    *(u16x8*)&Al[r][h * 16 + 8] = cal[1];
    *(u16x8*)&Wh[r][h * 16]     = cwh[0];
    *(u16x8*)&Wh[r][h * 16 + 8] = cwh[1];
    *(u16x8*)&Wl[r][h * 16]     = cwl[0];
    *(u16x8*)&Wl[r][h * 16 + 8] = cwl[1];

    if (k0 + 32 < K) {
#pragma unroll
      for (int j = 0; j < 4; ++j) {
        la[j] = *(const float4*)(Ap + (k0 + 32) + j * 4);
        lw[j] = wok ? *(const float4*)(Wp + (k0 + 32) + j * 4)
                    : make_float4(0.f, 0.f, 0.f, 0.f);
      }
    }
    __syncthreads();

    u16x8 fah[4], fal[4], fbh[4], fbl[4];
#pragma unroll
    for (int mt = 0; mt < 4; ++mt) {
      int row = wr * 64 + mt * 16 + ri;
      fah[mt] = *(const u16x8*)&Ah[row][kq];
      fal[mt] = *(const u16x8*)&Al[row][kq];
    }
#pragma unroll
    for (int nt = 0; nt < 4; ++nt) {
      int row = wc * 64 + nt * 16 + ri;
      fbh[nt] = *(const u16x8*)&Wh[row][kq];
      fbl[nt] = *(const u16x8*)&Wl[row][kq];
    }
#pragma unroll
    for (int mt = 0; mt < 4; ++mt)
#pragma unroll
      for (int nt = 0; nt < 4; ++nt) {
        f32x4 c = acc[mt][nt];
        c = mfma_bf16(fah[mt], fbl[nt], c);
        c = mfma_bf16(fal[mt], fbh[nt], c);
        c = mfma_bf16(fah[mt], fbh[nt], c);
        acc[mt][nt] = c;
      }
  }

  int rq = l >> 4;
#pragma unroll
  for (int mt = 0; mt < 4; ++mt) {
#pragma unroll
    for (int nt = 0; nt < 4; ++nt) {
      int col = n0 + wc * 64 + nt * 16 + ri;
      if (col < N) {
        float bv = bias ? bias[col] : 0.f;
        int row0 = m0 + wr * 64 + mt * 16 + rq * 4;
#pragma unroll
        for (int i = 0; i < 4; ++i) {
          size_t idx = (size_t)(row0 + i) * N + col;
          float o = acc[mt][nt][i] + bv;
          if (flags & 1) o += C[idx];
          if (flags & 2) o = nonsat_f(o);
          C[idx] = o;
        }
      }
    }
  }
}

// --------- repack: qkv (s,b,1536) -> Qh/Ql (scaled 0.125), Kh/Kl planes -----
// plane layout: [bh][t][64] u16
__global__ __launch_bounds__(256)
void repack_bf16(const float* __restrict__ qkv, u16* __restrict__ Qh,
                 u16* __restrict__ Ql, u16* __restrict__ Kh, u16* __restrict__ Kl) {
  int i = blockIdx.x * 256 + threadIdx.x;  // 1,048,576 float4-slots
  int d4 = i & 15;
  int t  = (i >> 4) & 1023;
  int h  = (i >> 14) & 7;
  int b  = i >> 17;
  const float4* src = (const float4*)qkv;
  size_t base = ((size_t)t * BATCH + b) * 384 + h * 16 + d4;
  float4 q = src[base];
  float4 k = src[base + 128];
  q.x *= 0.125f; q.y *= 0.125f; q.z *= 0.125f; q.w *= 0.125f;
  u16x4 qh, ql, kh, kl;
  {
    const float qf[4] = {q.x, q.y, q.z, q.w};
    const float kf[4] = {k.x, k.y, k.z, k.w};
#pragma unroll
    for (int e = 0; e < 4; ++e) {
      u16 hh, ll;
      split1(qf[e], hh, ll); qh[e] = hh; ql[e] = ll;
      split1(kf[e], hh, ll); kh[e] = hh; kl[e] = ll;
    }
  }
  size_t off = (((size_t)((b << 3) | h) * 1024 + t) * 64 + d4 * 4);
  *(u16x4*)(Qh + off) = qh;
  *(u16x4*)(Ql + off) = ql;
  *(u16x4*)(Kh + off) = kh;
  *(u16x4*)(Kl + off) = kl;
}

// --------- V transpose: qkv V section -> Vth/Vtl planes [bh][d][1024] -------
__global__ __launch_bounds__(256)
void vtrans_kernel(const float* __restrict__ qkv, u16* __restrict__ Vth,
                   u16* __restrict__ Vtl) {
  int kt = blockIdx.x;   // 64-key tile 0..15
  int bh = blockIdx.y;
  int b = bh >> 3, h = bh & 7;
  int t = threadIdx.x;
  __shared__ float Vs[64][68];
  int k0 = kt * 64;
#pragma unroll
  for (int it = 0; it < 4; ++it) {
    int f = it * 256 + t;
    int r = f >> 4, c4 = (f & 15) << 2;
    const float4 v = *(const float4*)(qkv + ((size_t)(k0 + r) * BATCH + b) * 1536 + 1024 + h * 64 + c4);
    Vs[r][c4] = v.x; Vs[r][c4 + 1] = v.y; Vs[r][c4 + 2] = v.z; Vs[r][c4 + 3] = v.w;
  }
  __syncthreads();
  int d = t & 63, kq = (t >> 6) * 16;
  u16x8 vh0, vl0, vh1, vl1;
#pragma unroll
  for (int j = 0; j < 8; ++j) {
    u16 hh, ll;
    split1(Vs[kq + j][d], hh, ll);
    vh0[j] = hh; vl0[j] = ll;
  }
#pragma unroll
  for (int j = 0; j < 8; ++j) {
    u16 hh, ll;
    split1(Vs[kq + 8 + j][d], hh, ll);
    vh1[j] = hh; vl1[j] = ll;
  }
  size_t ob = ((size_t)bh * 64 + d) * 1024 + k0 + kq;
  *(u16x8*)(Vth + ob) = vh0;
  *(u16x8*)(Vth + ob + 8) = vh1;
  *(u16x8*)(Vtl + ob) = vl0;
  *(u16x8*)(Vtl + ob + 8) = vl1;
}

// --------- MFMA flash attention ---------------------------------------------
// 128-query tile per block, 64-key tiles, 4 waves (32 q rows each).
// Q frags in registers; K/V^T staged bf16 hi/lo in LDS (XOR-swizzled rows,
// pitch 64 u16 = 128B); P (single bf16) aliases the K planes. LDS = 32 KB.
__global__ __launch_bounds__(256, 3)
void fattn_mfma(const u16* __restrict__ Qh, const u16* __restrict__ Ql,
                const u16* __restrict__ Kh, const u16* __restrict__ Kl,
                const u16* __restrict__ Vth, const u16* __restrict__ Vtl,
                float* __restrict__ ao) {
  __shared__ __align__(16) u16 SA[128 * 64];  // Q-hi | K-hi/K-lo | P
  __shared__ __align__(16) u16 SB[128 * 64];  // Q-lo | Vt-hi/Vt-lo
  int qi = (int)gridDim.x - 1 - blockIdx.x;   // heavy tiles dispatch first
  int bh = blockIdx.y;
  int b = bh >> 3, h = bh & 7;
  int t = threadIdx.x;
  int l = t & 63, w = t >> 6;
  int lr = l & 15, lc = l >> 4;
  int q0 = qi * 128;

  // ---- stage Q (hi->SA, lo->SB), swizzled
  const size_t qbase = ((size_t)bh * 1024 + q0) * 64;
#pragma unroll
  for (int it = 0; it < 4; ++it) {
    int idx = it * 256 + t;
    int r = idx >> 3, ch = idx & 7;
    u16x8 vh = *(const u16x8*)(Qh + qbase + (size_t)r * 64 + ch * 8);
    u16x8 vl = *(const u16x8*)(Ql + qbase + (size_t)r * 64 + ch * 8);
    int off = r * 128 + ((ch * 16) ^ ((r & 7) << 4));
    *(u16x8*)((char*)SA + off) = vh;
    *(u16x8*)((char*)SB + off) = vl;
  }
  __syncthreads();
  u16x8 qa[2][2][2];  // [hl][mi][ks]
#pragma unroll
  for (int mi = 0; mi < 2; ++mi)
#pragma unroll
    for (int ks = 0; ks < 2; ++ks) {
      int r = w * 32 + mi * 16 + lr;
      int off = r * 128 + ((ks * 64 + lc * 16) ^ ((r & 7) << 4));
      qa[0][mi][ks] = *(const u16x8*)((char*)SA + off);
      qa[1][mi][ks] = *(const u16x8*)((char*)SB + off);
    }

  f32x4 o[2][4];
  float m_i[2][4], l_i[2][4];
#pragma unroll
  for (int mi = 0; mi < 2; ++mi)
#pragma unroll
    for (int nf = 0; nf < 4; ++nf) o[mi][nf] = (f32x4){0.f, 0.f, 0.f, 0.f};
#pragma unroll
  for (int mi = 0; mi < 2; ++mi)
#pragma unroll
    for (int i = 0; i < 4; ++i) { m_i[mi][i] = -1e30f; l_i[mi][i] = 0.f; }

  const int ktmax = 2 * qi + 1;
  const size_t kbase0 = (size_t)bh * 1024 * 64;
  const size_t vbase0 = (size_t)bh * 64 * 1024;

  for (int kt = 0; kt <= ktmax; ++kt) {
    __syncthreads();  // Q-frag reads / previous PV reads done
    // ---- stage K (hi rows 0-63, lo rows 64-127 of SA) and Vt into SB
#pragma unroll
    for (int it = 0; it < 8; ++it) {
      int idx = it * 256 + t;      // 2048 16B chunks (wave-uniform plane id)
      int p = idx >> 9;
      int r = (idx >> 3) & 63;
      int ch = idx & 7;
      const u16* src;
      if (p == 0)      src = Kh  + kbase0 + (size_t)(kt * 64 + r) * 64 + ch * 8;
      else if (p == 1) src = Kl  + kbase0 + (size_t)(kt * 64 + r) * 64 + ch * 8;
      else if (p == 2) src = Vth + vbase0 + (size_t)r * 1024 + kt * 64 + ch * 8;
      else             src = Vtl + vbase0 + (size_t)r * 1024 + kt * 64 + ch * 8;
      u16x8 v = *(const u16x8*)src;
      int rr = (p & 1) ? (64 + r) : r;
      int off = rr * 128 + ((ch * 16) ^ ((rr & 7) << 4));
      if (p < 2) *(u16x8*)((char*)SA + off) = v;
      else       *(u16x8*)((char*)SB + off) = v;
    }
    __syncthreads();

    // ---- QK^T (split 3-term)
    f32x4 s[2][4];
#pragma unroll
    for (int mi = 0; mi < 2; ++mi)
#pragma unroll
      for (int nf = 0; nf < 4; ++nf) s[mi][nf] = (f32x4){0.f, 0.f, 0.f, 0.f};
#pragma unroll
    for (int ks = 0; ks < 2; ++ks) {
#pragma unroll
      for (int nf = 0; nf < 4; ++nf) {
        int rh = nf * 16 + lr;
        int rl = 64 + nf * 16 + lr;
        u16x8 kbh = *(const u16x8*)((char*)SA + rh * 128 + ((ks * 64 + lc * 16) ^ ((rh & 7) << 4)));
        u16x8 kbl = *(const u16x8*)((char*)SA + rl * 128 + ((ks * 64 + lc * 16) ^ ((rl & 7) << 4)));
#pragma unroll
        for (int mi = 0; mi < 2; ++mi) {
          s[mi][nf] = mfma_bf16(qa[0][mi][ks], kbl, s[mi][nf]);
          s[mi][nf] = mfma_bf16(qa[1][mi][ks], kbh, s[mi][nf]);
          s[mi][nf] = mfma_bf16(qa[0][mi][ks], kbh, s[mi][nf]);
        }
      }
    }

    if (kt >= 2 * qi) {  // diagonal region: causal mask
#pragma unroll
      for (int mi = 0; mi < 2; ++mi) {
        int rbase = q0 + w * 32 + mi * 16 + lc * 4;
#pragma unroll
        for (int nf = 0; nf < 4; ++nf) {
          int col = kt * 64 + nf * 16 + lr;
#pragma unroll
          for (int i = 0; i < 4; ++i)
            if (col > rbase + i) s[mi][nf][i] = -1e30f;
        }
      }
    }

    // ---- online softmax (row r held by 16-lane group; cols = 4 nf x lanes)
    float alpha[2][4];
#pragma unroll
    for (int mi = 0; mi < 2; ++mi)
#pragma unroll
      for (int i = 0; i < 4; ++i) {
        float rmax = fmaxf(fmaxf(s[mi][0][i], s[mi][1][i]),
                           fmaxf(s[mi][2][i], s[mi][3][i]));
        rmax = fmaxf(rmax, __shfl_xor(rmax, 1));
        rmax = fmaxf(rmax, __shfl_xor(rmax, 2));
        rmax = fmaxf(rmax, __shfl_xor(rmax, 4));
        rmax = fmaxf(rmax, __shfl_xor(rmax, 8));
        float mn = fmaxf(m_i[mi][i], rmax);
        alpha[mi][i] = __expf(m_i[mi][i] - mn);
        m_i[mi][i] = mn;
        float rs = 0.f;
#pragma unroll
        for (int nf = 0; nf < 4; ++nf) {
          float e = __expf(s[mi][nf][i] - mn);
          s[mi][nf][i] = e;
          rs += e;
        }
        rs += __shfl_xor(rs, 1);
        rs += __shfl_xor(rs, 2);
        rs += __shfl_xor(rs, 4);
        rs += __shfl_xor(rs, 8);
        l_i[mi][i] = l_i[mi][i] * alpha[mi][i] + rs;
      }

    __syncthreads();  // all QK reads of SA done
    // ---- P (bf16) -> SA[q][k], swizzled scalar stores
#pragma unroll
    for (int mi = 0; mi < 2; ++mi)
#pragma unroll
      for (int i = 0; i < 4; ++i) {
        int row = w * 32 + mi * 16 + lc * 4 + i;
        int sw = (row & 7) << 4;
#pragma unroll
        for (int nf = 0; nf < 4; ++nf) {
          int cb = (nf * 16 + lr) * 2;
          *(u16*)((char*)SA + row * 128 + (cb ^ sw)) = f2bf(s[mi][nf][i]);
        }
      }
    // rescale O
#pragma unroll
    for (int mi = 0; mi < 2; ++mi)
#pragma unroll
      for (int nf = 0; nf < 4; ++nf)
#pragma unroll
        for (int i = 0; i < 4; ++i) o[mi][nf][i] *= alpha[mi][i];
    __syncthreads();

    // ---- PV (P single-bf16 x split V)
#pragma unroll
    for (int ks = 0; ks < 2; ++ks) {
      u16x8 pa[2];
#pragma unroll
      for (int mi = 0; mi < 2; ++mi) {
        int r = w * 32 + mi * 16 + lr;
        pa[mi] = *(const u16x8*)((char*)SA + r * 128 + ((ks * 64 + lc * 16) ^ ((r & 7) << 4)));
      }
#pragma unroll
      for (int nf = 0; nf < 4; ++nf) {
        int rh = nf * 16 + lr, rl = 64 + nf * 16 + lr;
        u16x8 vbh = *(const u16x8*)((char*)SB + rh * 128 + ((ks * 64 + lc * 16) ^ ((rh & 7) << 4)));
        u16x8 vbl = *(const u16x8*)((char*)SB + rl * 128 + ((ks * 64 + lc * 16) ^ ((rl & 7) << 4)));
#pragma unroll
        for (int mi = 0; mi < 2; ++mi) {
          o[mi][nf] = mfma_bf16(pa[mi], vbl, o[mi][nf]);
          o[mi][nf] = mfma_bf16(pa[mi], vbh, o[mi][nf]);
        }
      }
    }
  }

  // ---- epilogue: normalize and write (s,b,E) layout
#pragma unroll
  for (int mi = 0; mi < 2; ++mi)
#pragma unroll
    for (int i = 0; i < 4; ++i) {
      float inv = __fdividef(1.f, l_i[mi][i]);
      int srow = q0 + w * 32 + mi * 16 + lc * 4 + i;
      float* op = ao + ((size_t)srow * BATCH + b) * EMB + h * DHEAD;
#pragma unroll
      for (int nf = 0; nf < 4; ++nf)
        op[nf * 16 + lr] = o[mi][nf][i] * inv;
    }
}

// --------- layernorm over E=512 of (xa+xb), optional nonsat ------------------
__global__ __launch_bounds__(256)
void ln_kernel(const float* __restrict__ xa, const float* __restrict__ xb,
               const float* __restrict__ g, const float* __restrict__ bet,
               float* __restrict__ out, int act) {
  int row = blockIdx.x;
  int t = threadIdx.x;
  size_t base = (size_t)row * EMB;
  float v0 = xa[base + t] + xb[base + t];
  float v1 = xa[base + t + 256] + xb[base + t + 256];
  float s = v0 + v1;
  float s2 = v0 * v0 + v1 * v1;
#pragma unroll
  for (int off = 32; off >= 1; off >>= 1) {
    s += __shfl_xor(s, off);
    s2 += __shfl_xor(s2, off);
  }
  __shared__ float ss[4], ss2[4];
  int w = t >> 6;
  if ((t & 63) == 0) { ss[w] = s; ss2[w] = s2; }
  __syncthreads();
  s = ss[0] + ss[1] + ss[2] + ss[3];
  s2 = ss2[0] + ss2[1] + ss2[2] + ss2[3];
  float mu = s * (1.f / EMB);
  float var = s2 * (1.f / EMB) - mu * mu;
  float rs = rsqrtf(var + 1e-5f);
  float o0 = (v0 - mu) * rs * g[t] + bet[t];
  float o1 = (v1 - mu) * rs * g[t + 256] + bet[t + 256];
  if (act) { o0 = nonsat_f(o0); o1 = nonsat_f(o1); }
  out[base + t] = o0;
  out[base + t + 256] = o1;
}

// --------- softmax over 128 (one wave per row) -------------------------------
__global__ __launch_bounds__(256)
void softmax128_kernel(float* __restrict__ L) {
  int row = blockIdx.x * 4 + (threadIdx.x >> 6);
  int lane = threadIdx.x & 63;
  float* p = L + (size_t)row * DSS;
  float a = p[lane], c = p[lane + 64];
  float m = fmaxf(a, c);
#pragma unroll
  for (int off = 32; off >= 1; off >>= 1) m = fmaxf(m, __shfl_xor(m, off));
  float e0 = __expf(a - m), e1 = __expf(c - m);
  float ssum = e0 + e1;
#pragma unroll
  for (int off = 32; off >= 1; off >>= 1) ssum += __shfl_xor(ssum, off);
  float inv = __fdividef(1.f, ssum);
  p[lane] = e0 * inv;
  p[lane + 64] = e1 * inv;
}

// --------- x2 = 0.5*(x1 + y) -------------------------------------------------
__global__ __launch_bounds__(256)
void avg_kernel(const float* __restrict__ a, const float* __restrict__ b,
                float* __restrict__ o) {
  int i = blockIdx.x * 256 + threadIdx.x;
  float4 x = ((const float4*)a)[i], y = ((const float4*)b)[i];
  float4 r = make_float4(0.5f * (x.x + y.x), 0.5f * (x.y + y.y),
                         0.5f * (x.z + y.z), 0.5f * (x.w + y.w));
  ((float4*)o)[i] = r;
}

// --------- controls = softmax3(hidden @ A_w^T + A_b), one wave per row -------
__global__ __launch_bounds__(256)
void controls_kernel(const float* __restrict__ hidden, const float* __restrict__ Aw,
                     const float* __restrict__ Ab, float* __restrict__ ctrl) {
  int row = blockIdx.x * 4 + (threadIdx.x >> 6);
  int lane = threadIdx.x & 63;
  const float* h = hidden + (size_t)row * DHID;
  float h0 = h[lane], h1 = h[lane + 64], h2 = h[lane + 128], h3 = h[lane + 192];
  float p0 = h0 * Aw[lane] + h1 * Aw[lane + 64] + h2 * Aw[lane + 128] + h3 * Aw[lane + 192];
  float p1 = h0 * Aw[256 + lane] + h1 * Aw[320 + lane] + h2 * Aw[384 + lane] + h3 * Aw[448 + lane];
  float p2 = h0 * Aw[512 + lane] + h1 * Aw[576 + lane] + h2 * Aw[640 + lane] + h3 * Aw[704 + lane];
#pragma unroll
  for (int off = 32; off >= 1; off >>= 1) {
    p0 += __shfl_xor(p0, off);
    p1 += __shfl_xor(p1, off);
    p2 += __shfl_xor(p2, off);
  }
  if (lane == 0) {
    p0 += Ab[0]; p1 += Ab[1]; p2 += Ab[2];
    float m = fmaxf(p0, fmaxf(p1, p2));
    float e0 = __expf(p0 - m), e1 = __expf(p1 - m), e2 = __expf(p2 - m);
    float inv = __fdividef(1.f, e0 + e1 + e2);
    ctrl[(size_t)row * 3 + 0] = e0 * inv;
    ctrl[(size_t)row * 3 + 1] = e1 * inv;
    ctrl[(size_t)row * 3 + 2] = e2 * inv;
  }
}

// --------- stack update: one block per (b,s) row -----------------------------
__global__ __launch_bounds__(256)
void stack_kernel(const float* __restrict__ sp, const float* __restrict__ si,
                  const float* __restrict__ ctrl, float* __restrict__ out) {
  int row = blockIdx.x;
  float c0 = ctrl[(size_t)row * 3 + 0];
  float c1 = ctrl[(size_t)row * 3 + 1];
  float c2 = ctrl[(size_t)row * 3 + 2];
  const float4* spr = (const float4*)(sp + (size_t)row * SDEPTH * SWIDTH);
  const float4* sir = (const float4*)(si + (size_t)row * SWIDTH);
  float4* o = (float4*)(out + (size_t)row * SDEPTH * SWIDTH);
  const int WV = SWIDTH / 4;  // 24
  for (int i = threadIdx.x; i < SDEPTH * WV; i += 256) {
    int d = i / WV;
    int w = i - d * WV;
    float4 cur = spr[i];
    float4 up = (d == 0) ? sir[w] : spr[i - WV];
    float4 dn = (d < SDEPTH - 1) ? spr[i + WV] : make_float4(0.f, 0.f, 0.f, 0.f);
    float4 r;
    r.x = c2 * cur.x + c0 * up.x + c1 * dn.x;
    r.y = c2 * cur.y + c0 * up.y + c1 * dn.y;
    r.z = c2 * cur.z + c0 * up.z + c1 * dn.z;
    r.w = c2 * cur.w + c0 * up.w + c1 * dn.w;
    o[i] = r;
  }
}

static inline void gemm(hipStream_t st, const float* A, int lda, int perm,
                        const float* W, int ldw, const float* bias, float* C,
                        int M, int N, int K, int flags) {
  dim3 g((N + 127) / 128, M / 128);
  hipLaunchKernelGGL(gemm_mfma, g, dim3(256), 0, st, A, lda, perm, W, ldw,
                     bias, C, M, N, K, flags);
}

extern "C" void kernel_launch(void* const* d_in, const int* in_sizes, int n_in,
                              void* d_out, int out_size, void* d_ws, size_t ws_size,
                              hipStream_t stream) {
  const float* x_in  = (const float*)d_in[0];
  const float* hprev = (const float*)d_in[1];
  const float* sprev = (const float*)d_in[2];
  const float* ipw   = (const float*)d_in[3];
  const float* ipb   = (const float*)d_in[4];
  const float* opw   = (const float*)d_in[5];
  const float* opb   = (const float*)d_in[6];
  const float* ln1g  = (const float*)d_in[7];
  const float* ln1b  = (const float*)d_in[8];
  const float* ln2g  = (const float*)d_in[9];
  const float* ln2b  = (const float*)d_in[10];
  const float* Ww    = (const float*)d_in[11];
  const float* Wb    = (const float*)d_in[12];
  const float* Rw    = (const float*)d_in[13];
  const float* Rb    = (const float*)d_in[14];
  const float* Pw    = (const float*)d_in[15];
  const float* Pb    = (const float*)d_in[16];
  const float* Vw    = (const float*)d_in[17];
  const float* Uw    = (const float*)d_in[18];
  const float* Aw    = (const float*)d_in[19];
  const float* Ab    = (const float*)d_in[20];
  const float* Dw    = (const float*)d_in[21];
  const float* Db    = (const float*)d_in[22];
  const float* ffiw  = (const float*)d_in[23];
  const float* ffib  = (const float*)d_in[24];
  const float* ffow  = (const float*)d_in[25];
  const float* ffob  = (const float*)d_in[26];

  // workspace layout (floats), total 141.7 MB:
  //   qkv    [0, 12.58M)          dead after repack/vtrans; ff1 reuses [0,16.78M)
  //   planes [12.58M, 25.17M)     Qh Ql Kh Kl Vth Vtl (u16), dead after fattn
  //   x1     [20.97M, 25.17M)     overlays Vth/Vtl (written after fattn)
  //   bufB   [25.17M, 29.36M)     AO -> Y -> FO
  //   bufC   [29.36M, 33.55M)     proj -> x2
  //   logits [33.55M, 34.60M)
  //   si     [34.60M, 35.39M)
  //   ctrl   [35.39M, 35.41M)
  float* ws     = (float*)d_ws;
  float* qkv    = ws;
  u16*   planes = (u16*)(ws + 12582912);
  u16*   Qh  = planes;
  u16*   Ql  = planes + 4194304;
  u16*   Kh  = planes + 8388608;
  u16*   Kl  = planes + 12582912;
  u16*   Vth = planes + 16777216;
  u16*   Vtl = planes + 20971520;
  float* ff1    = ws;
  float* x1     = ws + 20971520;
  float* bufB   = ws + 25165824;
  float* bufC   = ws + 29360128;
  float* logits = ws + 33554432;
  float* si     = ws + 34603008;
  float* ctrl   = ws + 35389440;

  float* out_x = (float*)d_out;
  float* out_h = out_x + 4194304;
  float* out_s = out_h + 2097152;

  const int M = S_LEN * BATCH;  // 8192

  // 1. qkv projection
  gemm(stream, x_in, EMB, 0, ipw, EMB, ipb, qkv, M, 3 * EMB, EMB, 0);
  // 2. repack Q/K to bf16 hi/lo planes
  hipLaunchKernelGGL(repack_bf16, dim3(4096), dim3(256), 0, stream, qkv, Qh, Ql, Kh, Kl);
  // 2b. V transpose to bf16 hi/lo planes [bh][d][t]
  hipLaunchKernelGGL(vtrans_kernel, dim3(16, 64), dim3(256), 0, stream, qkv, Vth, Vtl);
  // 3. MFMA flash attention -> bufB (pre-out_proj)
  hipLaunchKernelGGL(fattn_mfma, dim3(8, 64), dim3(256), 0, stream,
                     Qh, Ql, Kh, Kl, Vth, Vtl, bufB);
  // 4. out projection -> bufC
  gemm(stream, bufB, EMB, 0, opw, EMB, opb, bufC, M, EMB, EMB, 0);
  // 5. x1 = nonsat(LN(x_in + proj))
  hipLaunchKernelGGL(ln_kernel, dim3(M), dim3(256), 0, stream, x_in, bufC, ln1g,
                     ln1b, x1, 1);
  // 6. hidden = nonsat(x1'@W^T + Wb + hprev@R^T + Rb + stack0@P^T + Pb) -> d_out
  gemm(stream, x1, EMB, 1, Ww, EMB, Wb, out_h, M, DHID, EMB, 0);
  gemm(stream, hprev, DHID, 0, Rw, DHID, Rb, out_h, M, DHID, DHID, 1);
  gemm(stream, sprev, SDEPTH * SWIDTH, 0, Pw, SWIDTH, Pb, out_h, M, DHID, SWIDTH, 1 | 2);
  // 7. logits = [x1, hidden'] @ V^T
  gemm(stream, x1, EMB, 0, Vw, EMB + DHID, nullptr, logits, M, DSS, EMB, 0);
  gemm(stream, out_h, DHID, 2, Vw + EMB, EMB + DHID, nullptr, logits, M, DSS, DHID, 1);
  // 8. softmax over 128
  hipLaunchKernelGGL(softmax128_kernel, dim3(M / 4), dim3(256), 0, stream, logits);
  // 9. y = probs @ U^T -> bufB
  gemm(stream, logits, DSS, 0, Uw, DSS, nullptr, bufB, M, EMB, DSS, 0);
  // 10. x2 = 0.5*(x1 + y) -> bufC
  hipLaunchKernelGGL(avg_kernel, dim3(4096), dim3(256), 0, stream, x1, bufB, bufC);
  // 11. stack_inp = nonsat(hidden @ D^T + Db)
  gemm(stream, out_h, DHID, 0, Dw, DHID, Db, si, M, SWIDTH, DHID, 2);
  // 12. controls
  hipLaunchKernelGGL(controls_kernel, dim3(M / 4), dim3(256), 0, stream, out_h, Aw, Ab, ctrl);
  // 13. stack update -> d_out
  hipLaunchKernelGGL(stack_kernel, dim3(M), dim3(256), 0, stream, sprev, si, ctrl, out_s);
  // 14. ff1 = nonsat(x2 @ ffi^T + ffib)   (reuses qkv region)
  gemm(stream, bufC, EMB, 0, ffiw, EMB, ffib, ff1, M, DFF, EMB, 2);
  // 15. ff2 -> bufB
  gemm(stream, ff1, DFF, 0, ffow, DFF, ffob, bufB, M, EMB, DFF, 0);
  // 16. x_out = LN(x2 + ff)
  hipLaunchKernelGGL(ln_kernel, dim3(M), dim3(256), 0, stream, bufC, bufB, ln2g,
                     ln2b, out_x, 0);
}

// Round 5
// 1144.134 us; speedup vs baseline: 1.5251x; 1.2798x over previous
//
#include <hip/hip_runtime.h>
#include <math.h>

#define S_LEN 1024
#define BATCH 8
#define EMB 512
#define NHEAD 8
#define DHEAD 64
#define DHID 256
#define SDEPTH 48
#define SWIDTH 96
#define DFF 2048
#define DSS 128

typedef unsigned short u16;
typedef __attribute__((ext_vector_type(4))) float f32x4;
typedef __attribute__((ext_vector_type(4))) unsigned short u16x4;
typedef __attribute__((ext_vector_type(8))) unsigned short u16x8;
typedef __attribute__((ext_vector_type(8))) __bf16 bf16x8;

// GEMM epilogue flags
#define GF_ACC 1
#define GF_NONSAT 2
#define GF_WF 4
#define GF_WP 8

// nonsat(x): root of y^3/3 + y = x. Cardano closed form + 2 Newton polish.
// y = t - 1/t with t = cbrt(1.5x + sqrt(2.25x^2+1)); sign-symmetric form
// avoids cancellation for x<0.
// __builtin_amdgcn_exp2f = v_exp_f32 (2^x); __builtin_amdgcn_logf = v_log_f32 (log2).
__device__ __forceinline__ float nonsat_f(float x) {
  float a = fabsf(x) * 1.5f;
  float s = __builtin_sqrtf(a * a + 1.0f);
  float w = a + s;  // >= 1
  float tp = __builtin_amdgcn_exp2f(0.3333333433f * __builtin_amdgcn_logf(w));
  float ym = tp - __fdividef(1.0f, tp);
  float y = copysignf(ym, x);
#pragma unroll
  for (int i = 0; i < 2; ++i) {
    float y2 = y * y;
    y = __fdividef(0.6666666667f * y * y2 + x, y2 + 1.0f);
  }
  return y;
}

// ---- fp32 -> bf16 (RTNE) split helpers -------------------------------------
__device__ __forceinline__ u16 f2bf(float f) {
  unsigned u = __float_as_uint(f);
  unsigned r = (u + 0x7fffu + ((u >> 16) & 1u)) >> 16;
  return (u16)r;
}
__device__ __forceinline__ float bf2f(u16 h) {
  return __uint_as_float(((unsigned)h) << 16);
}
__device__ __forceinline__ void split1(float f, u16& hh, u16& ll) {
  hh = f2bf(f);
  ll = f2bf(f - bf2f(hh));
}

__device__ __forceinline__ f32x4 mfma_bf16(u16x8 a, u16x8 b, f32x4 c) {
  return __builtin_amdgcn_mfma_f32_16x16x32_bf16(
      __builtin_bit_cast(bf16x8, a), __builtin_bit_cast(bf16x8, b), c, 0, 0, 0);
}

// --------- convert_all: fp32 sources -> bf16 hi/lo planes (one pass) --------
struct ConvSeg { const float* src; u16* hi; u16* lo; };
struct ConvArgs { ConvSeg s[13]; };
// float4 counts per segment (seg2 = sprev stack slice, strided)
#define CONV_TOTAL4 2658304
__global__ __launch_bounds__(256)
void convert_all(ConvArgs a) {
  const int cum1 = 1048576, cum2 = 1572864, cum3 = 1769472, cum4 = 1966080,
            cum5 = 2031616, cum6 = 2064384, cum7 = 2080768, cum8 = 2086912,
            cum9 = 2111488, cum10 = 2127872, cum11 = 2134016, cum12 = 2396160;
  int i = blockIdx.x * 256 + threadIdx.x;
  if (i >= CONV_TOTAL4) return;
  int s = (i >= cum1) + (i >= cum2) + (i >= cum3) + (i >= cum4) + (i >= cum5) +
          (i >= cum6) + (i >= cum7) + (i >= cum8) + (i >= cum9) + (i >= cum10) +
          (i >= cum11) + (i >= cum12);
  const int cums[13] = {0, cum1, cum2, cum3, cum4, cum5, cum6,
                        cum7, cum8, cum9, cum10, cum11, cum12};
  int j = i - cums[s];
  const float* src = a.s[0].src;
  u16* hi = a.s[0].hi;
  u16* lo = a.s[0].lo;
#pragma unroll
  for (int k = 1; k < 13; ++k) {
    bool sel = (s == k);
    src = sel ? a.s[k].src : src;
    hi = sel ? a.s[k].hi : hi;
    lo = sel ? a.s[k].lo : lo;
  }
  size_t so, dof;
  if (s == 2) {  // sprev[:, :, 0, :]: rows of 24 float4, row stride 4608 floats
    int row = j / 24;
    int c = j - row * 24;
    so = (size_t)row * (SDEPTH * SWIDTH) + c * 4;
    dof = (size_t)j * 4;
  } else {
    so = (size_t)j * 4;
    dof = so;
  }
  float4 v = *(const float4*)(src + so);
  u16x4 hh, ll;
  const float f[4] = {v.x, v.y, v.z, v.w};
#pragma unroll
  for (int e = 0; e < 4; ++e) {
    u16 h_, l_;
    split1(f[e], h_, l_);
    hh[e] = h_; ll[e] = l_;
  }
  *(u16x4*)(hi + dof) = hh;
  *(u16x4*)(lo + dof) = ll;
}

// ---------------- plane-input split-bf16 MFMA GEMM --------------------------
// C[M,N] (+)= (Ah+Al)[M,K] @ (Wh+Wl)[N,K]^T + bias  (3-term split product)
// perm: 0 identity; 1: A row = ((m&1023)<<3)|(m>>10); 2: A row = ((m&7)<<10)|(m>>3)
// flags: GF_ACC accumulate Cf, GF_NONSAT epilogue, GF_WF write Cf, GF_WP write planes
// LDS: [2 mats][128 rows][64 u16] (hi cols 0-31 | lo cols 32-63), 128B pitch,
// XOR swizzle byte^=(row&7)<<4 -> conflict-free staging, 2-way (free) reads.
__global__ __launch_bounds__(256)
void gemm_mfma_p(const u16* __restrict__ Ah, const u16* __restrict__ Al,
                 int lda, int perm,
                 const u16* __restrict__ Wh, const u16* __restrict__ Wl,
                 int ldw, const float* __restrict__ bias,
                 float* __restrict__ Cf, u16* __restrict__ Ch,
                 u16* __restrict__ Cl,
                 int M, int N, int K, int flags) {
  __shared__ __align__(16) u16 SM[2 * 128 * 64];
  char* smb = (char*)SM;
  int t = threadIdx.x;
  int l = t & 63, w = t >> 6;
  int wr = w >> 1, wc = w & 1;
  int lr = l & 15, lc = l >> 4;
  int m0 = blockIdx.y * 128, n0 = blockIdx.x * 128;

  // staging: thread = chunk c (0..7; 0-3 hi, 4-7 lo) of rows r0+32j
  int c = t & 7, r0 = t >> 3;  // r0 in 0..31
  int ksub = (c & 3) * 8;
  const u16* Aplane = (c < 4) ? Ah : Al;
  const u16* Wplane = (c < 4) ? Wh : Wl;
  size_t aoff[4];
  const u16* wptr[4];
  bool wok[4];
#pragma unroll
  for (int j = 0; j < 4; ++j) {
    int mrow = m0 + r0 + 32 * j;
    int arow = mrow;
    if (perm == 1)      arow = ((mrow & 1023) << 3) | (mrow >> 10);
    else if (perm == 2) arow = ((mrow & 7) << 10) | (mrow >> 3);
    aoff[j] = (size_t)arow * lda + ksub;
    int nrow = n0 + r0 + 32 * j;
    wok[j] = nrow < N;
    wptr[j] = Wplane + (size_t)(wok[j] ? nrow : 0) * ldw + ksub;
  }
  int swz = (c * 16) ^ ((r0 & 7) << 4);
  int wofA[4], wofW[4];
#pragma unroll
  for (int j = 0; j < 4; ++j) {
    wofA[j] = (r0 + 32 * j) * 128 + swz;
    wofW[j] = (128 + r0 + 32 * j) * 128 + swz;
  }

  f32x4 acc[4][4];
#pragma unroll
  for (int mt = 0; mt < 4; ++mt)
#pragma unroll
    for (int nt = 0; nt < 4; ++nt)
      acc[mt][nt] = (f32x4){0.f, 0.f, 0.f, 0.f};

  const u16x8 z8 = {0, 0, 0, 0, 0, 0, 0, 0};
  u16x8 pa[4], pw[4];
#pragma unroll
  for (int j = 0; j < 4; ++j) {
    pa[j] = *(const u16x8*)(Aplane + aoff[j]);
    pw[j] = wok[j] ? *(const u16x8*)(wptr[j]) : z8;
  }

  for (int k0 = 0; k0 < K; k0 += 32) {
    __syncthreads();  // previous iteration's fragment reads done
#pragma unroll
    for (int j = 0; j < 4; ++j) {
      *(u16x8*)(smb + wofA[j]) = pa[j];
      *(u16x8*)(smb + wofW[j]) = pw[j];
    }
    if (k0 + 32 < K) {
      int kn = k0 + 32;
#pragma unroll
      for (int j = 0; j < 4; ++j) {
        pa[j] = *(const u16x8*)(Aplane + aoff[j] + kn);
        pw[j] = wok[j] ? *(const u16x8*)(wptr[j] + kn) : z8;
      }
    }
    __syncthreads();

    u16x8 fah[4], fal[4];
#pragma unroll
    for (int mt = 0; mt < 4; ++mt) {
      int row = wr * 64 + mt * 16 + lr;
      int sz = (row & 7) << 4;
      const char* rb = smb + row * 128;
      fah[mt] = *(const u16x8*)(rb + ((lc * 16) ^ sz));
      fal[mt] = *(const u16x8*)(rb + ((64 + lc * 16) ^ sz));
    }
#pragma unroll
    for (int nt = 0; nt < 4; ++nt) {
      int row = 128 + wc * 64 + nt * 16 + lr;
      int sz = (row & 7) << 4;
      const char* rb = smb + row * 128;
      u16x8 fbh = *(const u16x8*)(rb + ((lc * 16) ^ sz));
      u16x8 fbl = *(const u16x8*)(rb + ((64 + lc * 16) ^ sz));
#pragma unroll
      for (int mt = 0; mt < 4; ++mt) {
        f32x4 cc = acc[mt][nt];
        cc = mfma_bf16(fah[mt], fbl, cc);
        cc = mfma_bf16(fal[mt], fbh, cc);
        cc = mfma_bf16(fah[mt], fbh, cc);
        acc[mt][nt] = cc;
      }
    }
  }

  int rq = l >> 4;
#pragma unroll
  for (int mt = 0; mt < 4; ++mt) {
#pragma unroll
    for (int nt = 0; nt < 4; ++nt) {
      int col = n0 + wc * 64 + nt * 16 + lr;
      if (col < N) {
        float bv = bias ? bias[col] : 0.f;
        int row0 = m0 + wr * 64 + mt * 16 + rq * 4;
#pragma unroll
        for (int i = 0; i < 4; ++i) {
          size_t idx = (size_t)(row0 + i) * N + col;
          float o = acc[mt][nt][i] + bv;
          if (flags & GF_ACC) o += Cf[idx];
          if (flags & GF_NONSAT) o = nonsat_f(o);
          if (flags & GF_WF) Cf[idx] = o;
          if (flags & GF_WP) {
            u16 hh, ll;
            split1(o, hh, ll);
            Ch[idx] = hh;
            Cl[idx] = ll;
          }
        }
      }
    }
  }
}

// --------- repack: qkv (s,b,1536) -> Qh/Ql (scaled 0.125), Kh/Kl planes -----
// plane layout: [bh][t][64] u16
__global__ __launch_bounds__(256)
void repack_bf16(const float* __restrict__ qkv, u16* __restrict__ Qh,
                 u16* __restrict__ Ql, u16* __restrict__ Kh, u16* __restrict__ Kl) {
  int i = blockIdx.x * 256 + threadIdx.x;  // 1,048,576 float4-slots
  int d4 = i & 15;
  int t  = (i >> 4) & 1023;
  int h  = (i >> 14) & 7;
  int b  = i >> 17;
  const float4* src = (const float4*)qkv;
  size_t base = ((size_t)t * BATCH + b) * 384 + h * 16 + d4;
  float4 q = src[base];
  float4 k = src[base + 128];
  q.x *= 0.125f; q.y *= 0.125f; q.z *= 0.125f; q.w *= 0.125f;
  u16x4 qh, ql, kh, kl;
  {
    const float qf[4] = {q.x, q.y, q.z, q.w};
    const float kf[4] = {k.x, k.y, k.z, k.w};
#pragma unroll
    for (int e = 0; e < 4; ++e) {
      u16 hh, ll;
      split1(qf[e], hh, ll); qh[e] = hh; ql[e] = ll;
      split1(kf[e], hh, ll); kh[e] = hh; kl[e] = ll;
    }
  }
  size_t off = (((size_t)((b << 3) | h) * 1024 + t) * 64 + d4 * 4);
  *(u16x4*)(Qh + off) = qh;
  *(u16x4*)(Ql + off) = ql;
  *(u16x4*)(Kh + off) = kh;
  *(u16x4*)(Kl + off) = kl;
}

// --------- V transpose: qkv V section -> Vth/Vtl planes [bh][d][1024] -------
__global__ __launch_bounds__(256)
void vtrans_kernel(const float* __restrict__ qkv, u16* __restrict__ Vth,
                   u16* __restrict__ Vtl) {
  int kt = blockIdx.x;   // 64-key tile 0..15
  int bh = blockIdx.y;
  int b = bh >> 3, h = bh & 7;
  int t = threadIdx.x;
  __shared__ float Vs[64][68];
  int k0 = kt * 64;
#pragma unroll
  for (int it = 0; it < 4; ++it) {
    int f = it * 256 + t;
    int r = f >> 4, c4 = (f & 15) << 2;
    const float4 v = *(const float4*)(qkv + ((size_t)(k0 + r) * BATCH + b) * 1536 + 1024 + h * 64 + c4);
    Vs[r][c4] = v.x; Vs[r][c4 + 1] = v.y; Vs[r][c4 + 2] = v.z; Vs[r][c4 + 3] = v.w;
  }
  __syncthreads();
  int d = t & 63, kq = (t >> 6) * 16;
  u16x8 vh0, vl0, vh1, vl1;
#pragma unroll
  for (int j = 0; j < 8; ++j) {
    u16 hh, ll;
    split1(Vs[kq + j][d], hh, ll);
    vh0[j] = hh; vl0[j] = ll;
  }
#pragma unroll
  for (int j = 0; j < 8; ++j) {
    u16 hh, ll;
    split1(Vs[kq + 8 + j][d], hh, ll);
    vh1[j] = hh; vl1[j] = ll;
  }
  size_t ob = ((size_t)bh * 64 + d) * 1024 + k0 + kq;
  *(u16x8*)(Vth + ob) = vh0;
  *(u16x8*)(Vth + ob + 8) = vh1;
  *(u16x8*)(Vtl + ob) = vl0;
  *(u16x8*)(Vtl + ob + 8) = vl1;
}

// --------- MFMA flash attention ---------------------------------------------
// 128-query tile per block, 64-key tiles, 4 waves (32 q rows each).
// Q frags in registers; K/V^T staged bf16 hi/lo in LDS (XOR-swizzled rows,
// pitch 64 u16 = 128B); P (single bf16) aliases the K planes. LDS = 32 KB.
// Epilogue writes AO as bf16 hi/lo planes (feeds out-proj GEMM).
__global__ __launch_bounds__(256, 3)
void fattn_mfma(const u16* __restrict__ Qh, const u16* __restrict__ Ql,
                const u16* __restrict__ Kh, const u16* __restrict__ Kl,
                const u16* __restrict__ Vth, const u16* __restrict__ Vtl,
                u16* __restrict__ AOh, u16* __restrict__ AOl) {
  __shared__ __align__(16) u16 SA[128 * 64];  // Q-hi | K-hi/K-lo | P
  __shared__ __align__(16) u16 SB[128 * 64];  // Q-lo | Vt-hi/Vt-lo
  int qi = (int)gridDim.x - 1 - blockIdx.x;   // heavy tiles dispatch first
  int bh = blockIdx.y;
  int b = bh >> 3, h = bh & 7;
  int t = threadIdx.x;
  int l = t & 63, w = t >> 6;
  int lr = l & 15, lc = l >> 4;
  int q0 = qi * 128;

  const size_t qbase = ((size_t)bh * 1024 + q0) * 64;
#pragma unroll
  for (int it = 0; it < 4; ++it) {
    int idx = it * 256 + t;
    int r = idx >> 3, ch = idx & 7;
    u16x8 vh = *(const u16x8*)(Qh + qbase + (size_t)r * 64 + ch * 8);
    u16x8 vl = *(const u16x8*)(Ql + qbase + (size_t)r * 64 + ch * 8);
    int off = r * 128 + ((ch * 16) ^ ((r & 7) << 4));
    *(u16x8*)((char*)SA + off) = vh;
    *(u16x8*)((char*)SB + off) = vl;
  }
  __syncthreads();
  u16x8 qa[2][2][2];  // [hl][mi][ks]
#pragma unroll
  for (int mi = 0; mi < 2; ++mi)
#pragma unroll
    for (int ks = 0; ks < 2; ++ks) {
      int r = w * 32 + mi * 16 + lr;
      int off = r * 128 + ((ks * 64 + lc * 16) ^ ((r & 7) << 4));
      qa[0][mi][ks] = *(const u16x8*)((char*)SA + off);
      qa[1][mi][ks] = *(const u16x8*)((char*)SB + off);
    }

  f32x4 o[2][4];
  float m_i[2][4], l_i[2][4];
#pragma unroll
  for (int mi = 0; mi < 2; ++mi)
#pragma unroll
    for (int nf = 0; nf < 4; ++nf) o[mi][nf] = (f32x4){0.f, 0.f, 0.f, 0.f};
#pragma unroll
  for (int mi = 0; mi < 2; ++mi)
#pragma unroll
    for (int i = 0; i < 4; ++i) { m_i[mi][i] = -1e30f; l_i[mi][i] = 0.f; }

  const int ktmax = 2 * qi + 1;
  const size_t kbase0 = (size_t)bh * 1024 * 64;
  const size_t vbase0 = (size_t)bh * 64 * 1024;

  for (int kt = 0; kt <= ktmax; ++kt) {
    __syncthreads();
#pragma unroll
    for (int it = 0; it < 8; ++it) {
      int idx = it * 256 + t;
      int p = idx >> 9;
      int r = (idx >> 3) & 63;
      int ch = idx & 7;
      const u16* src;
      if (p == 0)      src = Kh  + kbase0 + (size_t)(kt * 64 + r) * 64 + ch * 8;
      else if (p == 1) src = Kl  + kbase0 + (size_t)(kt * 64 + r) * 64 + ch * 8;
      else if (p == 2) src = Vth + vbase0 + (size_t)r * 1024 + kt * 64 + ch * 8;
      else             src = Vtl + vbase0 + (size_t)r * 1024 + kt * 64 + ch * 8;
      u16x8 v = *(const u16x8*)src;
      int rr = (p & 1) ? (64 + r) : r;
      int off = rr * 128 + ((ch * 16) ^ ((rr & 7) << 4));
      if (p < 2) *(u16x8*)((char*)SA + off) = v;
      else       *(u16x8*)((char*)SB + off) = v;
    }
    __syncthreads();

    f32x4 s[2][4];
#pragma unroll
    for (int mi = 0; mi < 2; ++mi)
#pragma unroll
      for (int nf = 0; nf < 4; ++nf) s[mi][nf] = (f32x4){0.f, 0.f, 0.f, 0.f};
#pragma unroll
    for (int ks = 0; ks < 2; ++ks) {
#pragma unroll
      for (int nf = 0; nf < 4; ++nf) {
        int rh = nf * 16 + lr;
        int rl = 64 + nf * 16 + lr;
        u16x8 kbh = *(const u16x8*)((char*)SA + rh * 128 + ((ks * 64 + lc * 16) ^ ((rh & 7) << 4)));
        u16x8 kbl = *(const u16x8*)((char*)SA + rl * 128 + ((ks * 64 + lc * 16) ^ ((rl & 7) << 4)));
#pragma unroll
        for (int mi = 0; mi < 2; ++mi) {
          s[mi][nf] = mfma_bf16(qa[0][mi][ks], kbl, s[mi][nf]);
          s[mi][nf] = mfma_bf16(qa[1][mi][ks], kbh, s[mi][nf]);
          s[mi][nf] = mfma_bf16(qa[0][mi][ks], kbh, s[mi][nf]);
        }
      }
    }

    if (kt >= 2 * qi) {
#pragma unroll
      for (int mi = 0; mi < 2; ++mi) {
        int rbase = q0 + w * 32 + mi * 16 + lc * 4;
#pragma unroll
        for (int nf = 0; nf < 4; ++nf) {
          int col = kt * 64 + nf * 16 + lr;
#pragma unroll
          for (int i = 0; i < 4; ++i)
            if (col > rbase + i) s[mi][nf][i] = -1e30f;
        }
      }
    }

    float alpha[2][4];
#pragma unroll
    for (int mi = 0; mi < 2; ++mi)
#pragma unroll
      for (int i = 0; i < 4; ++i) {
        float rmax = fmaxf(fmaxf(s[mi][0][i], s[mi][1][i]),
                           fmaxf(s[mi][2][i], s[mi][3][i]));
        rmax = fmaxf(rmax, __shfl_xor(rmax, 1));
        rmax = fmaxf(rmax, __shfl_xor(rmax, 2));
        rmax = fmaxf(rmax, __shfl_xor(rmax, 4));
        rmax = fmaxf(rmax, __shfl_xor(rmax, 8));
        float mn = fmaxf(m_i[mi][i], rmax);
        alpha[mi][i] = __expf(m_i[mi][i] - mn);
        m_i[mi][i] = mn;
        float rs = 0.f;
#pragma unroll
        for (int nf = 0; nf < 4; ++nf) {
          float e = __expf(s[mi][nf][i] - mn);
          s[mi][nf][i] = e;
          rs += e;
        }
        rs += __shfl_xor(rs, 1);
        rs += __shfl_xor(rs, 2);
        rs += __shfl_xor(rs, 4);
        rs += __shfl_xor(rs, 8);
        l_i[mi][i] = l_i[mi][i] * alpha[mi][i] + rs;
      }

    __syncthreads();
#pragma unroll
    for (int mi = 0; mi < 2; ++mi)
#pragma unroll
      for (int i = 0; i < 4; ++i) {
        int row = w * 32 + mi * 16 + lc * 4 + i;
        int sw = (row & 7) << 4;
#pragma unroll
        for (int nf = 0; nf < 4; ++nf) {
          int cb = (nf * 16 + lr) * 2;
          *(u16*)((char*)SA + row * 128 + (cb ^ sw)) = f2bf(s[mi][nf][i]);
        }
      }
#pragma unroll
    for (int mi = 0; mi < 2; ++mi)
#pragma unroll
      for (int nf = 0; nf < 4; ++nf)
#pragma unroll
        for (int i = 0; i < 4; ++i) o[mi][nf][i] *= alpha[mi][i];
    __syncthreads();

#pragma unroll
    for (int ks = 0; ks < 2; ++ks) {
      u16x8 pa[2];
#pragma unroll
      for (int mi = 0; mi < 2; ++mi) {
        int r = w * 32 + mi * 16 + lr;
        pa[mi] = *(const u16x8*)((char*)SA + r * 128 + ((ks * 64 + lc * 16) ^ ((r & 7) << 4)));
      }
#pragma unroll
      for (int nf = 0; nf < 4; ++nf) {
        int rh = nf * 16 + lr, rl = 64 + nf * 16 + lr;
        u16x8 vbh = *(const u16x8*)((char*)SB + rh * 128 + ((ks * 64 + lc * 16) ^ ((rh & 7) << 4)));
        u16x8 vbl = *(const u16x8*)((char*)SB + rl * 128 + ((ks * 64 + lc * 16) ^ ((rl & 7) << 4)));
#pragma unroll
        for (int mi = 0; mi < 2; ++mi) {
          o[mi][nf] = mfma_bf16(pa[mi], vbl, o[mi][nf]);
          o[mi][nf] = mfma_bf16(pa[mi], vbh, o[mi][nf]);
        }
      }
    }
  }

#pragma unroll
  for (int mi = 0; mi < 2; ++mi)
#pragma unroll
    for (int i = 0; i < 4; ++i) {
      float inv = __fdividef(1.f, l_i[mi][i]);
      int srow = q0 + w * 32 + mi * 16 + lc * 4 + i;
      size_t base = ((size_t)srow * BATCH + b) * EMB + h * DHEAD;
#pragma unroll
      for (int nf = 0; nf < 4; ++nf) {
        u16 hh, ll;
        split1(o[mi][nf][i] * inv, hh, ll);
        AOh[base + nf * 16 + lr] = hh;
        AOl[base + nf * 16 + lr] = ll;
      }
    }
}

// --------- layernorm over E=512 of (xa+xb), optional nonsat + plane out ------
__global__ __launch_bounds__(256)
void ln_kernel(const float* __restrict__ xa, const float* __restrict__ xb,
               const float* __restrict__ g, const float* __restrict__ bet,
               float* __restrict__ out, u16* __restrict__ oh,
               u16* __restrict__ ol, int act) {
  int row = blockIdx.x;
  int t = threadIdx.x;
  size_t base = (size_t)row * EMB;
  float v0 = xa[base + t] + xb[base + t];
  float v1 = xa[base + t + 256] + xb[base + t + 256];
  float s = v0 + v1;
  float s2 = v0 * v0 + v1 * v1;
#pragma unroll
  for (int off = 32; off >= 1; off >>= 1) {
    s += __shfl_xor(s, off);
    s2 += __shfl_xor(s2, off);
  }
  __shared__ float ss[4], ss2[4];
  int w = t >> 6;
  if ((t & 63) == 0) { ss[w] = s; ss2[w] = s2; }
  __syncthreads();
  s = ss[0] + ss[1] + ss[2] + ss[3];
  s2 = ss2[0] + ss2[1] + ss2[2] + ss2[3];
  float mu = s * (1.f / EMB);
  float var = s2 * (1.f / EMB) - mu * mu;
  float rs = rsqrtf(var + 1e-5f);
  float o0 = (v0 - mu) * rs * g[t] + bet[t];
  float o1 = (v1 - mu) * rs * g[t + 256] + bet[t + 256];
  if (act) { o0 = nonsat_f(o0); o1 = nonsat_f(o1); }
  out[base + t] = o0;
  out[base + t + 256] = o1;
  if (oh) {
    u16 hh, ll;
    split1(o0, hh, ll); oh[base + t] = hh; ol[base + t] = ll;
    split1(o1, hh, ll); oh[base + t + 256] = hh; ol[base + t + 256] = ll;
  }
}

// --------- softmax over 128 -> bf16 hi/lo planes -----------------------------
__global__ __launch_bounds__(256)
void softmax128_kernel(const float* __restrict__ L, u16* __restrict__ PH,
                       u16* __restrict__ PL) {
  int row = blockIdx.x * 4 + (threadIdx.x >> 6);
  int lane = threadIdx.x & 63;
  const float* p = L + (size_t)row * DSS;
  float a = p[lane], c = p[lane + 64];
  float m = fmaxf(a, c);
#pragma unroll
  for (int off = 32; off >= 1; off >>= 1) m = fmaxf(m, __shfl_xor(m, off));
  float e0 = __expf(a - m), e1 = __expf(c - m);
  float ssum = e0 + e1;
#pragma unroll
  for (int off = 32; off >= 1; off >>= 1) ssum += __shfl_xor(ssum, off);
  float inv = __fdividef(1.f, ssum);
  u16 hh, ll;
  size_t ob = (size_t)row * DSS;
  split1(e0 * inv, hh, ll);
  PH[ob + lane] = hh; PL[ob + lane] = ll;
  split1(e1 * inv, hh, ll);
  PH[ob + lane + 64] = hh; PL[ob + lane + 64] = ll;
}

// --------- x2 = 0.5*(x1 + y), fp32 + planes ---------------------------------
__global__ __launch_bounds__(256)
void avg_kernel(const float* __restrict__ a, const float* __restrict__ b,
                float* __restrict__ o, u16* __restrict__ oh,
                u16* __restrict__ ol) {
  int i = blockIdx.x * 256 + threadIdx.x;
  float4 x = ((const float4*)a)[i], y = ((const float4*)b)[i];
  float4 r = make_float4(0.5f * (x.x + y.x), 0.5f * (x.y + y.y),
                         0.5f * (x.z + y.z), 0.5f * (x.w + y.w));
  ((float4*)o)[i] = r;
  u16x4 hh, ll;
  const float f[4] = {r.x, r.y, r.z, r.w};
#pragma unroll
  for (int e = 0; e < 4; ++e) {
    u16 h_, l_;
    split1(f[e], h_, l_);
    hh[e] = h_; ll[e] = l_;
  }
  *(u16x4*)(oh + (size_t)i * 4) = hh;
  *(u16x4*)(ol + (size_t)i * 4) = ll;
}

// --------- controls = softmax3(hidden @ A_w^T + A_b), one wave per row -------
__global__ __launch_bounds__(256)
void controls_kernel(const float* __restrict__ hidden, const float* __restrict__ Aw,
                     const float* __restrict__ Ab, float* __restrict__ ctrl) {
  int row = blockIdx.x * 4 + (threadIdx.x >> 6);
  int lane = threadIdx.x & 63;
  const float* h = hidden + (size_t)row * DHID;
  float h0 = h[lane], h1 = h[lane + 64], h2 = h[lane + 128], h3 = h[lane + 192];
  float p0 = h0 * Aw[lane] + h1 * Aw[lane + 64] + h2 * Aw[lane + 128] + h3 * Aw[lane + 192];
  float p1 = h0 * Aw[256 + lane] + h1 * Aw[320 + lane] + h2 * Aw[384 + lane] + h3 * Aw[448 + lane];
  float p2 = h0 * Aw[512 + lane] + h1 * Aw[576 + lane] + h2 * Aw[640 + lane] + h3 * Aw[704 + lane];
#pragma unroll
  for (int off = 32; off >= 1; off >>= 1) {
    p0 += __shfl_xor(p0, off);
    p1 += __shfl_xor(p1, off);
    p2 += __shfl_xor(p2, off);
  }
  if (lane == 0) {
    p0 += Ab[0]; p1 += Ab[1]; p2 += Ab[2];
    float m = fmaxf(p0, fmaxf(p1, p2));
    float e0 = __expf(p0 - m), e1 = __expf(p1 - m), e2 = __expf(p2 - m);
    float inv = __fdividef(1.f, e0 + e1 + e2);
    ctrl[(size_t)row * 3 + 0] = e0 * inv;
    ctrl[(size_t)row * 3 + 1] = e1 * inv;
    ctrl[(size_t)row * 3 + 2] = e2 * inv;
  }
}

// --------- stack update: one block per (b,s) row -----------------------------
__global__ __launch_bounds__(256)
void stack_kernel(const float* __restrict__ sp, const float* __restrict__ si,
                  const float* __restrict__ ctrl, float* __restrict__ out) {
  int row = blockIdx.x;
  float c0 = ctrl[(size_t)row * 3 + 0];
  float c1 = ctrl[(size_t)row * 3 + 1];
  float c2 = ctrl[(size_t)row * 3 + 2];
  const float4* spr = (const float4*)(sp + (size_t)row * SDEPTH * SWIDTH);
  const float4* sir = (const float4*)(si + (size_t)row * SWIDTH);
  float4* o = (float4*)(out + (size_t)row * SDEPTH * SWIDTH);
  const int WV = SWIDTH / 4;  // 24
  for (int i = threadIdx.x; i < SDEPTH * WV; i += 256) {
    int d = i / WV;
    int w = i - d * WV;
    float4 cur = spr[i];
    float4 up = (d == 0) ? sir[w] : spr[i - WV];
    float4 dn = (d < SDEPTH - 1) ? spr[i + WV] : make_float4(0.f, 0.f, 0.f, 0.f);
    float4 r;
    r.x = c2 * cur.x + c0 * up.x + c1 * dn.x;
    r.y = c2 * cur.y + c0 * up.y + c1 * dn.y;
    r.z = c2 * cur.z + c0 * up.z + c1 * dn.z;
    r.w = c2 * cur.w + c0 * up.w + c1 * dn.w;
    o[i] = r;
  }
}

static inline void gemm_p(hipStream_t st, const u16* Ah, const u16* Al, int lda,
                          int perm, const u16* Wh, const u16* Wl, int ldw,
                          const float* bias, float* Cf, u16* Ch, u16* Cl,
                          int M, int N, int K, int flags) {
  dim3 g((N + 127) / 128, M / 128);
  hipLaunchKernelGGL(gemm_mfma_p, g, dim3(256), 0, st, Ah, Al, lda, perm,
                     Wh, Wl, ldw, bias, Cf, Ch, Cl, M, N, K, flags);
}

extern "C" void kernel_launch(void* const* d_in, const int* in_sizes, int n_in,
                              void* d_out, int out_size, void* d_ws, size_t ws_size,
                              hipStream_t stream) {
  const float* x_in  = (const float*)d_in[0];
  const float* hprev = (const float*)d_in[1];
  const float* sprev = (const float*)d_in[2];
  const float* ipw   = (const float*)d_in[3];
  const float* ipb   = (const float*)d_in[4];
  const float* opw   = (const float*)d_in[5];
  const float* opb   = (const float*)d_in[6];
  const float* ln1g  = (const float*)d_in[7];
  const float* ln1b  = (const float*)d_in[8];
  const float* ln2g  = (const float*)d_in[9];
  const float* ln2b  = (const float*)d_in[10];
  const float* Ww    = (const float*)d_in[11];
  const float* Wb    = (const float*)d_in[12];
  const float* Rw    = (const float*)d_in[13];
  const float* Rb    = (const float*)d_in[14];
  const float* Pw    = (const float*)d_in[15];
  const float* Pb    = (const float*)d_in[16];
  const float* Vw    = (const float*)d_in[17];
  const float* Uw    = (const float*)d_in[18];
  const float* Aw    = (const float*)d_in[19];
  const float* Ab    = (const float*)d_in[20];
  const float* Dw    = (const float*)d_in[21];
  const float* Db    = (const float*)d_in[22];
  const float* ffiw  = (const float*)d_in[23];
  const float* ffib  = (const float*)d_in[24];
  const float* ffow  = (const float*)d_in[25];
  const float* ffob  = (const float*)d_in[26];

  // workspace layout (floats), temporal aliasing; total 35,414,016 fl = 141.7MB
  float* ws = (float*)d_ws;
  float* qkv     = ws;                  // [0,12.58M)  S1-S2
  float* yfp     = ws + 4194304;        // S9-S10
  float* x1fp    = ws + 8388608;        // S5-S10
  float* projB   = ws + 19922944;       // S4-S5
  float* x2fp    = ws + 19922944;       // S10-S16 (projB dead)
  float* logitsF = ws + 24117248;       // S7-S8
  float* ff2out  = ws + 25165824;       // S15-S16
  float* si      = ws + 34603008;
  float* ctrl    = ws + 35389440;

  u16* x_inPh = (u16*)(ws + 12582912);  u16* x_inPl = x_inPh + 4194304;  // S0-S1
  u16* Qh  = (u16*)(ws + 12582912);     // attn planes S2-S3 (overwrite x_inP)
  u16* Ql  = Qh + 4194304;
  u16* Kh  = Ql + 4194304;
  u16* Kl  = Kh + 4194304;
  u16* Vth = Kl + 4194304;
  u16* Vtl = Vth + 4194304;
  u16* AOh = (u16*)ws;                  u16* AOl = AOh + 4194304;        // S3-S4
  u16* x1Ph = (u16*)(ws + 12582912);    u16* x1Pl = x1Ph + 4194304;      // S5-S7
  u16* hidPh = (u16*)(ws + 16777216);   u16* hidPl = hidPh + 2097152;    // S6c-S11
  u16* logPh = (u16*)(ws + 18874368);   u16* logPl = logPh + 1048576;    // S8-S9
  u16* hprevPh = (u16*)(ws + 25165824); u16* hprevPl = hprevPh + 2097152;// S0-S6b
  u16* sprevPh = (u16*)(ws + 27262976); u16* sprevPl = sprevPh + 786432; // S0-S6c
  u16* x2Ph = (u16*)(ws + 25165824);    u16* x2Pl = x2Ph + 4194304;      // S10-S14
  u16* ff1Ph = (u16*)ws;                u16* ff1Pl = ff1Ph + 16777216;   // S14-S15

  u16* wp = (u16*)(ws + 31047680);      // weight planes, whole launch
  u16* ipwH  = wp;            u16* ipwL  = wp + 786432;
  u16* opwH  = wp + 1572864;  u16* opwL  = wp + 1835008;
  u16* WwH   = wp + 2097152;  u16* WwL   = wp + 2228224;
  u16* RwH   = wp + 2359296;  u16* RwL   = wp + 2424832;
  u16* PwH   = wp + 2490368;  u16* PwL   = wp + 2514944;
  u16* VwH   = wp + 2539520;  u16* VwL   = wp + 2637824;
  u16* UwH   = wp + 2736128;  u16* UwL   = wp + 2801664;
  u16* DwH   = wp + 2867200;  u16* DwL   = wp + 2891776;
  u16* ffiwH = wp + 2916352;  u16* ffiwL = wp + 3964928;
  u16* ffowH = wp + 5013504;  u16* ffowL = wp + 6062080;

  float* out_x = (float*)d_out;
  float* out_h = out_x + 4194304;
  float* out_s = out_h + 2097152;

  const int M = S_LEN * BATCH;  // 8192

  // S0: one-pass conversion of all external GEMM inputs to bf16 hi/lo planes
  ConvArgs ca;
  ca.s[0]  = {x_in,  x_inPh,  x_inPl};
  ca.s[1]  = {hprev, hprevPh, hprevPl};
  ca.s[2]  = {sprev, sprevPh, sprevPl};  // strided stack slice
  ca.s[3]  = {ipw,   ipwH,    ipwL};
  ca.s[4]  = {opw,   opwH,    opwL};
  ca.s[5]  = {Ww,    WwH,     WwL};
  ca.s[6]  = {Rw,    RwH,     RwL};
  ca.s[7]  = {Pw,    PwH,     PwL};
  ca.s[8]  = {Vw,    VwH,     VwL};
  ca.s[9]  = {Uw,    UwH,     UwL};
  ca.s[10] = {Dw,    DwH,     DwL};
  ca.s[11] = {ffiw,  ffiwH,   ffiwL};
  ca.s[12] = {ffow,  ffowH,   ffowL};
  hipLaunchKernelGGL(convert_all, dim3((CONV_TOTAL4 + 255) / 256), dim3(256), 0, stream, ca);

  // S1: qkv projection (fp32 out for repack/vtrans)
  gemm_p(stream, x_inPh, x_inPl, EMB, 0, ipwH, ipwL, EMB, ipb,
         qkv, nullptr, nullptr, M, 3 * EMB, EMB, GF_WF);
  // S2: repack Q/K + V transpose to attention planes
  hipLaunchKernelGGL(repack_bf16, dim3(4096), dim3(256), 0, stream, qkv, Qh, Ql, Kh, Kl);
  hipLaunchKernelGGL(vtrans_kernel, dim3(16, 64), dim3(256), 0, stream, qkv, Vth, Vtl);
  // S3: MFMA flash attention -> AO planes
  hipLaunchKernelGGL(fattn_mfma, dim3(8, 64), dim3(256), 0, stream,
                     Qh, Ql, Kh, Kl, Vth, Vtl, AOh, AOl);
  // S4: out projection -> projB fp32
  gemm_p(stream, AOh, AOl, EMB, 0, opwH, opwL, EMB, opb,
         projB, nullptr, nullptr, M, EMB, EMB, GF_WF);
  // S5: x1 = nonsat(LN(x_in + proj)) -> fp32 + planes
  hipLaunchKernelGGL(ln_kernel, dim3(M), dim3(256), 0, stream, x_in, projB,
                     ln1g, ln1b, x1fp, x1Ph, x1Pl, 1);
  // S6: hidden = nonsat(x1'@W^T + Wb + hprev@R^T + Rb + stack0@P^T + Pb)
  gemm_p(stream, x1Ph, x1Pl, EMB, 1, WwH, WwL, EMB, Wb,
         out_h, nullptr, nullptr, M, DHID, EMB, GF_WF);
  gemm_p(stream, hprevPh, hprevPl, DHID, 0, RwH, RwL, DHID, Rb,
         out_h, nullptr, nullptr, M, DHID, DHID, GF_WF | GF_ACC);
  gemm_p(stream, sprevPh, sprevPl, SWIDTH, 0, PwH, PwL, SWIDTH, Pb,
         out_h, hidPh, hidPl, M, DHID, SWIDTH, GF_WF | GF_ACC | GF_NONSAT | GF_WP);
  // S7: logits = [x1, hidden'] @ V^T
  gemm_p(stream, x1Ph, x1Pl, EMB, 0, VwH, VwL, EMB + DHID, nullptr,
         logitsF, nullptr, nullptr, M, DSS, EMB, GF_WF);
  gemm_p(stream, hidPh, hidPl, DHID, 2, VwH + EMB, VwL + EMB, EMB + DHID, nullptr,
         logitsF, nullptr, nullptr, M, DSS, DHID, GF_WF | GF_ACC);
  // S8: softmax over 128 -> prob planes
  hipLaunchKernelGGL(softmax128_kernel, dim3(M / 4), dim3(256), 0, stream,
                     logitsF, logPh, logPl);
  // S9: y = probs @ U^T -> yfp
  gemm_p(stream, logPh, logPl, DSS, 0, UwH, UwL, DSS, nullptr,
         yfp, nullptr, nullptr, M, EMB, DSS, GF_WF);
  // S10: x2 = 0.5*(x1 + y) -> fp32 + planes
  hipLaunchKernelGGL(avg_kernel, dim3(4096), dim3(256), 0, stream, x1fp, yfp,
                     x2fp, x2Ph, x2Pl);
  // S11: stack_inp = nonsat(hidden @ D^T + Db) -> si fp32
  gemm_p(stream, hidPh, hidPl, DHID, 0, DwH, DwL, DHID, Db,
         si, nullptr, nullptr, M, SWIDTH, DHID, GF_WF | GF_NONSAT);
  // S12: controls
  hipLaunchKernelGGL(controls_kernel, dim3(M / 4), dim3(256), 0, stream, out_h, Aw, Ab, ctrl);
  // S13: stack update -> d_out
  hipLaunchKernelGGL(stack_kernel, dim3(M), dim3(256), 0, stream, sprev, si, ctrl, out_s);
  // S14: ff1 = nonsat(x2 @ ffi^T + ffib) -> planes only
  gemm_p(stream, x2Ph, x2Pl, EMB, 0, ffiwH, ffiwL, EMB, ffib,
         nullptr, ff1Ph, ff1Pl, M, DFF, EMB, GF_NONSAT | GF_WP);
  // S15: ff2 -> ff2out fp32
  gemm_p(stream, ff1Ph, ff1Pl, DFF, 0, ffowH, ffowL, DFF, ffob,
         ff2out, nullptr, nullptr, M, EMB, DFF, GF_WF);
  // S16: x_out = LN(x2 + ff)
  hipLaunchKernelGGL(ln_kernel, dim3(M), dim3(256), 0, stream, x2fp, ff2out,
                     ln2g, ln2b, out_x, nullptr, nullptr, 0);
}